// Round 4
// baseline (6071.107 us; speedup 1.0000x reference)
//
#include <hip/hip_runtime.h>
#include <math.h>

#define HD   256
#define FIN  32
#define NP   8192
#define PGH  4096
#define NLVL 15
#define TN   16    // nodes per block tile

__device__ __forceinline__ float lrelu(float x) { return x > 0.f ? x : 0.1f * x; }

// cooperative stage of n4 float4s global -> LDS (n4 <= 2048), 256 threads
__device__ __forceinline__ void stage_w(const float* __restrict__ g, float* l, int n4, int tid)
{
    const float4* g4 = (const float4*)g;
    float4* l4 = (float4*)l;
    float4 tmp[8];
#pragma unroll
    for (int u = 0; u < 8; u++) { int q = tid + u * 256; if (q < n4) tmp[u] = g4[q]; }
#pragma unroll
    for (int u = 0; u < 8; u++) { int q = tid + u * 256; if (q < n4) l4[q] = tmp[u]; }
}

// ---------------- pi kernel: prev_h = mlp(delay) ----------------
__global__ __launch_bounds__(256) void pi_kernel(
    const float* __restrict__ delay,
    const float* __restrict__ w1, const float* __restrict__ b1,
    const float* __restrict__ w2, const float* __restrict__ b2,
    float* __restrict__ outh)
{
    __shared__ float g1[TN][132];
    __shared__ float wbuf[32 * 256];
    const int tid = threadIdx.x;
    const int node0 = blockIdx.x * TN;

    for (int t = tid; t < TN * 128; t += 256) {
        int i = t >> 7, jj = t & 127;
        g1[i][jj] = lrelu(delay[node0 + i] * w1[jj] + b1[jj]);
    }

    const int j = (tid & 63) * 4;
    const int rg = (tid >> 6) * 4;
    float acc[4][4];
    float4 bv = *(const float4*)&b2[j];
#pragma unroll
    for (int ri = 0; ri < 4; ri++) { acc[ri][0] = bv.x; acc[ri][1] = bv.y; acc[ri][2] = bv.z; acc[ri][3] = bv.w; }

    for (int kc = 0; kc < 128; kc += 32) {
        __syncthreads();
        stage_w(w2 + (size_t)kc * 256, wbuf, 32 * 64, tid);
        __syncthreads();
        for (int k = 0; k < 32; k += 4) {
            float4 x0 = *(const float4*)&g1[rg + 0][kc + k];
            float4 x1 = *(const float4*)&g1[rg + 1][kc + k];
            float4 x2v = *(const float4*)&g1[rg + 2][kc + k];
            float4 x3 = *(const float4*)&g1[rg + 3][kc + k];
#define PIK(comp, off) { float4 wv = *(const float4*)&wbuf[(k + off) * 256 + j]; \
    acc[0][0] += x0.comp * wv.x; acc[0][1] += x0.comp * wv.y; acc[0][2] += x0.comp * wv.z; acc[0][3] += x0.comp * wv.w; \
    acc[1][0] += x1.comp * wv.x; acc[1][1] += x1.comp * wv.y; acc[1][2] += x1.comp * wv.z; acc[1][3] += x1.comp * wv.w; \
    acc[2][0] += x2v.comp * wv.x; acc[2][1] += x2v.comp * wv.y; acc[2][2] += x2v.comp * wv.z; acc[2][3] += x2v.comp * wv.w; \
    acc[3][0] += x3.comp * wv.x; acc[3][1] += x3.comp * wv.y; acc[3][2] += x3.comp * wv.z; acc[3][3] += x3.comp * wv.w; }
            PIK(x, 0) PIK(y, 1) PIK(z, 2) PIK(w, 3)
#undef PIK
        }
    }
#pragma unroll
    for (int ri = 0; ri < 4; ri++)
        *(float4*)&outh[(node0 + rg + ri) * HD + j] =
            make_float4(acc[ri][0], acc[ri][1], acc[ri][2], acc[ri][3]);
}

// ---------------- per-level kernel: blocks 0..255 gate, 256..511 mod ----------------
__global__ __launch_bounds__(256) void level_kernel(
    const float* __restrict__ prevh, float* __restrict__ nexth,
    const float* __restrict__ feat, const float* __restrict__ bitpos,
    const int* __restrict__ srcidx,
    const float* __restrict__ g_w1, const float* __restrict__ g_b1,
    const float* __restrict__ g_w2, const float* __restrict__ g_b2,
    const float* __restrict__ m_w1, const float* __restrict__ m_b1,
    const float* __restrict__ m_w2, const float* __restrict__ m_b2,
    const float* __restrict__ t_w1, const float* __restrict__ t_b1,
    const float* __restrict__ t_w2, const float* __restrict__ t_b2,
    const float* __restrict__ p_w1, const float* __restrict__ p_b1,
    const float* __restrict__ p_w2, const float* __restrict__ p_b2,
    const float* __restrict__ av,
    int level, int apply_relu)
{
    __shared__ float x_lds[TN][292];
    __shared__ float h1_lds[TN][132];
    __shared__ float wbuf[64 * 128];     // 32 KB: [64][128] for GEMM1 / [32][256] for GEMM2
    __shared__ int   src_lds[TN * 8];
    __shared__ float bp_lds[TN * 8];
    __shared__ float dstf_lds[TN][32];
    __shared__ float ztt_lds[TN][32];
    __shared__ float smdot_lds[TN * 8];
    __shared__ float alpha_lds[TN * 8];
    __shared__ float xbp_lds[TN];
    __shared__ float av_lds[320];
    __shared__ float tw2av_lds[32];
    __shared__ float pw2av_lds[32];
    __shared__ float bias_av[2];

    const int tid = threadIdx.x;
    const bool is_gate = (blockIdx.x < 256);
    const int node0 = is_gate ? (blockIdx.x * TN) : (PGH + ((int)blockIdx.x - 256) * TN);

    if (tid < TN * 8) src_lds[tid] = srcidx[(level * NP + node0) * 8 + tid];

    if (is_gate) {
        for (int t = tid; t < TN * 32; t += 256) {
            int i = t >> 5, k = t & 31;
            x_lds[i][256 + k] = feat[((level + 1) * NP + node0 + i) * FIN + k];
        }
        __syncthreads();
        // gather + per-channel softmax over fanin, 4-node chunks (32 loads in flight)
        for (int s0 = 0; s0 < TN; s0 += 4) {
            float mg[4][8];
#pragma unroll
            for (int s = 0; s < 4; s++) {
                const int* sp = &src_lds[(s0 + s) * 8];
#pragma unroll
                for (int f = 0; f < 8; f++) mg[s][f] = prevh[sp[f] * HD + tid];
            }
#pragma unroll
            for (int s = 0; s < 4; s++) {
                float mx = -1e30f;
#pragma unroll
                for (int f = 0; f < 8; f++) mx = fmaxf(mx, mg[s][f]);
                float ssum = 0.f, ws = 0.f;
#pragma unroll
                for (int f = 0; f < 8; f++) {
                    float e = __expf(mg[s][f] - mx);
                    ssum += e; ws += mg[s][f] * e;
                }
                x_lds[s0 + s][tid] = ws / ssum;
            }
        }
        __syncthreads();
    } else {
        if (tid < TN * 8) bp_lds[tid] = bitpos[(level * NP + node0) * 8 + tid];
        for (int t = tid; t < TN * 32; t += 256) {
            int i = t >> 5, k = t & 31;
            dstf_lds[i][k] = feat[((level + 1) * NP + node0 + i) * FIN + k];
        }
        for (int t = tid; t < 320; t += 256) av_lds[t] = av[t];
        __syncthreads();

        // ztt = lrelu(dstf @ t_w1 + t_b1)
        for (int t = tid; t < TN * 32; t += 256) {
            int i = t >> 5, jj = t & 31;
            float a = t_b1[jj];
#pragma unroll 8
            for (int k = 0; k < 32; k++) a += dstf_lds[i][k] * t_w1[k * 32 + jj];
            ztt_lds[i][jj] = lrelu(a);
        }
        // fold attn_vec through second MLP layers (exact linear reassociation)
        if (tid < 32) {
            float s = 0.f;
#pragma unroll 8
            for (int jj = 0; jj < 32; jj++) s += t_w2[tid * 32 + jj] * av_lds[jj];
            tw2av_lds[tid] = s;
        } else if (tid < 64) {
            int k = tid - 32;
            float s = 0.f;
#pragma unroll 8
            for (int jj = 0; jj < 32; jj++) s += p_w2[k * 32 + jj] * av_lds[32 + jj];
            pw2av_lds[k] = s;
        } else if (tid == 64) {
            float s = 0.f;
#pragma unroll 8
            for (int jj = 0; jj < 32; jj++) s += t_b2[jj] * av_lds[jj];
            bias_av[0] = s;
        } else if (tid == 65) {
            float s = 0.f;
#pragma unroll 8
            for (int jj = 0; jj < 32; jj++) s += p_b2[jj] * av_lds[32 + jj];
            bias_av[1] = s;
        }
        // sm . av[64:320] per gathered row: 4 waves x 32 rows, 8-row load chunks
        {
            const int wave = tid >> 6, lane = tid & 63;
            float4 av4 = *(const float4*)&av_lds[64 + lane * 4];
            for (int t0 = 0; t0 < 32; t0 += 8) {
                float4 xv[8];
#pragma unroll
                for (int t = 0; t < 8; t++) {
                    int rr = wave + 4 * (t0 + t);
                    xv[t] = *(const float4*)&prevh[src_lds[rr] * HD + lane * 4];
                }
#pragma unroll
                for (int t = 0; t < 8; t++) {
                    float pz = xv[t].x * av4.x + xv[t].y * av4.y + xv[t].z * av4.z + xv[t].w * av4.w;
#pragma unroll
                    for (int off = 32; off > 0; off >>= 1) pz += __shfl_xor(pz, off);
                    if (lane == 0) smdot_lds[wave + 4 * (t0 + t)] = pz;
                }
            }
        }
        __syncthreads();

        // logits + softmax over fanin: tid = i*16 + f*2 + jg
        {
            const int jg = tid & 1, f = (tid >> 1) & 7, i = tid >> 4;
            const float bpv = bp_lds[i * 8 + f];
            float part = 0.f;
            const int k0 = jg * 16;
#pragma unroll
            for (int k = k0; k < k0 + 16; k++) {
                float h1pk = lrelu(bpv * p_w1[k] + p_b1[k]);
                part += h1pk * pw2av_lds[k];
                part += ztt_lds[i][k] * tw2av_lds[k];
            }
            part += __shfl_xor(part, 1);
            float logit = part + bias_av[0] + bias_av[1] + smdot_lds[i * 8 + f];
            float mx = logit;
            mx = fmaxf(mx, __shfl_xor(mx, 2));
            mx = fmaxf(mx, __shfl_xor(mx, 4));
            mx = fmaxf(mx, __shfl_xor(mx, 8));
            float e = __expf(logit - mx);
            float ssum = e;
            ssum += __shfl_xor(ssum, 2);
            ssum += __shfl_xor(ssum, 4);
            ssum += __shfl_xor(ssum, 8);
            float alpha = e / ssum;
            if (jg == 0) alpha_lds[i * 8 + f] = alpha;
            float ab = alpha * bpv;
            ab += __shfl_xor(ab, 2);
            ab += __shfl_xor(ab, 4);
            ab += __shfl_xor(ab, 8);
            if ((tid & 15) == 0) xbp_lds[i] = ab;
        }
        __syncthreads();

        // neigh_m, 4-node chunks (32 loads in flight) + assemble x
        for (int s0 = 0; s0 < TN; s0 += 4) {
            float mg[4][8];
#pragma unroll
            for (int s = 0; s < 4; s++) {
                const int* sp = &src_lds[(s0 + s) * 8];
#pragma unroll
                for (int f = 0; f < 8; f++) mg[s][f] = prevh[sp[f] * HD + tid];
            }
#pragma unroll
            for (int s = 0; s < 4; s++) {
                const float* ap = &alpha_lds[(s0 + s) * 8];
                float a = 0.f;
#pragma unroll
                for (int f = 0; f < 8; f++) a += ap[f] * mg[s][f];
                x_lds[s0 + s][tid] = a;
            }
        }
        if (tid < TN) x_lds[tid][256] = xbp_lds[tid];
        for (int t = tid; t < TN * 32; t += 256) {
            int i = t >> 5, k = t & 31;
            x_lds[i][257 + k] = dstf_lds[i][k];
        }
        __syncthreads();
    }

    // ---------- GEMM1: (TN x K1) @ (K1 x 128) + b1, leaky; weights LDS-staged ----------
    const float* w1 = is_gate ? g_w1 : m_w1;
    const float* b1 = is_gate ? g_b1 : m_b1;
    {
        const int j = (tid & 63) * 2;
        const int rg = (tid >> 6) * 4;
        float acc[4][2];
        float2 bv = *(const float2*)&b1[j];
#pragma unroll
        for (int ri = 0; ri < 4; ri++) { acc[ri][0] = bv.x; acc[ri][1] = bv.y; }

        for (int kc = 0; kc < 288; kc += 64) {
            const int KC = (288 - kc) < 64 ? (288 - kc) : 64;
            __syncthreads();
            stage_w(w1 + (size_t)kc * 128, wbuf, KC * 32, tid);
            __syncthreads();
            for (int k = 0; k < KC; k += 4) {
                float4 x0 = *(const float4*)&x_lds[rg + 0][kc + k];
                float4 x1 = *(const float4*)&x_lds[rg + 1][kc + k];
                float4 x2v = *(const float4*)&x_lds[rg + 2][kc + k];
                float4 x3 = *(const float4*)&x_lds[rg + 3][kc + k];
#define G1K(comp, off) { float2 wv = *(const float2*)&wbuf[(k + off) * 128 + j]; \
    acc[0][0] += x0.comp * wv.x; acc[0][1] += x0.comp * wv.y; \
    acc[1][0] += x1.comp * wv.x; acc[1][1] += x1.comp * wv.y; \
    acc[2][0] += x2v.comp * wv.x; acc[2][1] += x2v.comp * wv.y; \
    acc[3][0] += x3.comp * wv.x; acc[3][1] += x3.comp * wv.y; }
                G1K(x, 0) G1K(y, 1) G1K(z, 2) G1K(w, 3)
#undef G1K
            }
        }
        if (!is_gate) {
            float2 wt = *(const float2*)&w1[288 * 128 + j];
#pragma unroll
            for (int ri = 0; ri < 4; ri++) {
                float xb = x_lds[rg + ri][288];
                acc[ri][0] += xb * wt.x; acc[ri][1] += xb * wt.y;
            }
        }
#pragma unroll
        for (int ri = 0; ri < 4; ri++)
            *(float2*)&h1_lds[rg + ri][j] = make_float2(lrelu(acc[ri][0]), lrelu(acc[ri][1]));
    }
    __syncthreads();

    // ---------- GEMM2: (TN x 128) @ (128 x 256) + b2 (+relu); weights LDS-staged ----------
    const float* w2 = is_gate ? g_w2 : m_w2;
    const float* b2 = is_gate ? g_b2 : m_b2;
    {
        const int j = (tid & 63) * 4;
        const int rg = (tid >> 6) * 4;
        float acc[4][4];
        float4 bv = *(const float4*)&b2[j];
#pragma unroll
        for (int ri = 0; ri < 4; ri++) { acc[ri][0] = bv.x; acc[ri][1] = bv.y; acc[ri][2] = bv.z; acc[ri][3] = bv.w; }

        for (int kc = 0; kc < 128; kc += 32) {
            __syncthreads();
            stage_w(w2 + (size_t)kc * 256, wbuf, 32 * 64, tid);
            __syncthreads();
            for (int k = 0; k < 32; k += 4) {
                float4 x0 = *(const float4*)&h1_lds[rg + 0][kc + k];
                float4 x1 = *(const float4*)&h1_lds[rg + 1][kc + k];
                float4 x2v = *(const float4*)&h1_lds[rg + 2][kc + k];
                float4 x3 = *(const float4*)&h1_lds[rg + 3][kc + k];
#define G2K(comp, off) { float4 wv = *(const float4*)&wbuf[(k + off) * 256 + j]; \
    acc[0][0] += x0.comp * wv.x; acc[0][1] += x0.comp * wv.y; acc[0][2] += x0.comp * wv.z; acc[0][3] += x0.comp * wv.w; \
    acc[1][0] += x1.comp * wv.x; acc[1][1] += x1.comp * wv.y; acc[1][2] += x1.comp * wv.z; acc[1][3] += x1.comp * wv.w; \
    acc[2][0] += x2v.comp * wv.x; acc[2][1] += x2v.comp * wv.y; acc[2][2] += x2v.comp * wv.z; acc[2][3] += x2v.comp * wv.w; \
    acc[3][0] += x3.comp * wv.x; acc[3][1] += x3.comp * wv.y; acc[3][2] += x3.comp * wv.z; acc[3][3] += x3.comp * wv.w; }
                G2K(x, 0) G2K(y, 1) G2K(z, 2) G2K(w, 3)
#undef G2K
            }
        }
#pragma unroll
        for (int ri = 0; ri < 4; ri++) {
            if (apply_relu) {
#pragma unroll
                for (int ci = 0; ci < 4; ci++) acc[ri][ci] = fmaxf(acc[ri][ci], 0.f);
            }
            *(float4*)&nexth[(node0 + rg + ri) * HD + j] =
                make_float4(acc[ri][0], acc[ri][1], acc[ri][2], acc[ri][3]);
        }
    }
}

// ---------------- final kernel: glob mlp + concat + out mlp (fused) ----------------
__global__ __launch_bounds__(256) void final_kernel(
    const float* __restrict__ prevh, const float* __restrict__ pofeat,
    const float* __restrict__ gl_w1, const float* __restrict__ gl_b1,
    const float* __restrict__ gl_w2, const float* __restrict__ gl_b2,
    const float* __restrict__ o_w1, const float* __restrict__ o_b1,
    const float* __restrict__ o_w2, const float* __restrict__ o_b2,
    float* __restrict__ out)
{
    __shared__ float x2[TN][516];
    __shared__ float g1[TN][132];
    __shared__ float wbuf[32 * 256];
    __shared__ float ow2_lds[256];

    const int tid = threadIdx.x;
    const int node0 = blockIdx.x * TN;
    const int j = (tid & 63) * 4;
    const int rg = (tid >> 6) * 4;

    for (int q = tid; q < TN * 64; q += 256) {
        int i = q >> 6, c4 = (q & 63) * 4;
        *(float4*)&x2[i][c4] = *(const float4*)&prevh[(node0 + i) * HD + c4];
    }
    for (int t = tid; t < TN * 128; t += 256) {
        int i = t >> 7, jj = t & 127;
        g1[i][jj] = lrelu(pofeat[node0 + i] * gl_w1[jj] + gl_b1[jj]);
    }
    ow2_lds[tid] = o_w2[tid];

    // glob layer 2: (TN x 128)@(128 x 256) -> x2 cols 256..511, staged
    {
        float acc[4][4];
        float4 bv = *(const float4*)&gl_b2[j];
#pragma unroll
        for (int ri = 0; ri < 4; ri++) { acc[ri][0] = bv.x; acc[ri][1] = bv.y; acc[ri][2] = bv.z; acc[ri][3] = bv.w; }
        for (int kc = 0; kc < 128; kc += 32) {
            __syncthreads();
            stage_w(gl_w2 + (size_t)kc * 256, wbuf, 32 * 64, tid);
            __syncthreads();
            for (int k = 0; k < 32; k += 4) {
                float4 x0 = *(const float4*)&g1[rg + 0][kc + k];
                float4 x1 = *(const float4*)&g1[rg + 1][kc + k];
                float4 x2v = *(const float4*)&g1[rg + 2][kc + k];
                float4 x3 = *(const float4*)&g1[rg + 3][kc + k];
#define GLK(comp, off) { float4 wv = *(const float4*)&wbuf[(k + off) * 256 + j]; \
    acc[0][0] += x0.comp * wv.x; acc[0][1] += x0.comp * wv.y; acc[0][2] += x0.comp * wv.z; acc[0][3] += x0.comp * wv.w; \
    acc[1][0] += x1.comp * wv.x; acc[1][1] += x1.comp * wv.y; acc[1][2] += x1.comp * wv.z; acc[1][3] += x1.comp * wv.w; \
    acc[2][0] += x2v.comp * wv.x; acc[2][1] += x2v.comp * wv.y; acc[2][2] += x2v.comp * wv.z; acc[2][3] += x2v.comp * wv.w; \
    acc[3][0] += x3.comp * wv.x; acc[3][1] += x3.comp * wv.y; acc[3][2] += x3.comp * wv.z; acc[3][3] += x3.comp * wv.w; }
                GLK(x, 0) GLK(y, 1) GLK(z, 2) GLK(w, 3)
#undef GLK
            }
        }
#pragma unroll
        for (int ri = 0; ri < 4; ri++)
            *(float4*)&x2[rg + ri][256 + j] = make_float4(acc[ri][0], acc[ri][1], acc[ri][2], acc[ri][3]);
    }
    __syncthreads();

    // out layer 1 (staged) fused with out layer 2 (wave reduction)
    {
        float acc[4][4];
        float4 bv = *(const float4*)&o_b1[j];
#pragma unroll
        for (int ri = 0; ri < 4; ri++) { acc[ri][0] = bv.x; acc[ri][1] = bv.y; acc[ri][2] = bv.z; acc[ri][3] = bv.w; }
        for (int kc = 0; kc < 512; kc += 32) {
            __syncthreads();
            stage_w(o_w1 + (size_t)kc * 256, wbuf, 32 * 64, tid);
            __syncthreads();
            for (int k = 0; k < 32; k += 4) {
                float4 x0 = *(const float4*)&x2[rg + 0][kc + k];
                float4 x1 = *(const float4*)&x2[rg + 1][kc + k];
                float4 x2v = *(const float4*)&x2[rg + 2][kc + k];
                float4 x3 = *(const float4*)&x2[rg + 3][kc + k];
#define O1K(comp, off) { float4 wv = *(const float4*)&wbuf[(k + off) * 256 + j]; \
    acc[0][0] += x0.comp * wv.x; acc[0][1] += x0.comp * wv.y; acc[0][2] += x0.comp * wv.z; acc[0][3] += x0.comp * wv.w; \
    acc[1][0] += x1.comp * wv.x; acc[1][1] += x1.comp * wv.y; acc[1][2] += x1.comp * wv.z; acc[1][3] += x1.comp * wv.w; \
    acc[2][0] += x2v.comp * wv.x; acc[2][1] += x2v.comp * wv.y; acc[2][2] += x2v.comp * wv.z; acc[2][3] += x2v.comp * wv.w; \
    acc[3][0] += x3.comp * wv.x; acc[3][1] += x3.comp * wv.y; acc[3][2] += x3.comp * wv.z; acc[3][3] += x3.comp * wv.w; }
                O1K(x, 0) O1K(y, 1) O1K(z, 2) O1K(w, 3)
#undef O1K
            }
        }
        // out layer 2: wave covers cols 0..255 for rows rg..rg+3
        float4 wv = *(const float4*)&ow2_lds[j];
        float ob = o_b2[0];
#pragma unroll
        for (int ri = 0; ri < 4; ri++) {
            float p = lrelu(acc[ri][0]) * wv.x + lrelu(acc[ri][1]) * wv.y
                    + lrelu(acc[ri][2]) * wv.z + lrelu(acc[ri][3]) * wv.w;
#pragma unroll
            for (int off = 1; off < 64; off <<= 1) p += __shfl_xor(p, off);
            if ((tid & 63) == 0) out[node0 + rg + ri] = p + ob;
        }
    }
}

extern "C" void kernel_launch(void* const* d_in, const int* in_sizes, int n_in,
                              void* d_out, int out_size, void* d_ws, size_t ws_size,
                              hipStream_t stream)
{
    const float* delay    = (const float*)d_in[0];
    const float* feat     = (const float*)d_in[1];
    const float* bitpos   = (const float*)d_in[2];
    const float* pofeat   = (const float*)d_in[3];
    const int*   srcidx   = (const int*)  d_in[4];
    const float* pi_w1    = (const float*)d_in[5];
    const float* pi_b1    = (const float*)d_in[6];
    const float* pi_w2    = (const float*)d_in[7];
    const float* pi_b2    = (const float*)d_in[8];
    const float* gate_w1  = (const float*)d_in[9];
    const float* gate_b1  = (const float*)d_in[10];
    const float* gate_w2  = (const float*)d_in[11];
    const float* gate_b2  = (const float*)d_in[12];
    const float* mod_w1   = (const float*)d_in[13];
    const float* mod_b1   = (const float*)d_in[14];
    const float* mod_w2   = (const float*)d_in[15];
    const float* mod_b2   = (const float*)d_in[16];
    const float* type_w1  = (const float*)d_in[17];
    const float* type_b1  = (const float*)d_in[18];
    const float* type_w2  = (const float*)d_in[19];
    const float* type_b2  = (const float*)d_in[20];
    const float* pos_w1   = (const float*)d_in[21];
    const float* pos_b1   = (const float*)d_in[22];
    const float* pos_w2   = (const float*)d_in[23];
    const float* pos_b2   = (const float*)d_in[24];
    const float* attn_vec = (const float*)d_in[25];
    const float* glob_w1  = (const float*)d_in[26];
    const float* glob_b1  = (const float*)d_in[27];
    const float* glob_w2  = (const float*)d_in[28];
    const float* glob_b2  = (const float*)d_in[29];
    const float* out_w1   = (const float*)d_in[30];
    const float* out_b1   = (const float*)d_in[31];
    const float* out_w2   = (const float*)d_in[32];
    const float* out_b2   = (const float*)d_in[33];

    float* buf0 = (float*)d_ws;
    float* buf1 = buf0 + (size_t)NP * HD;

    pi_kernel<<<NP / TN, 256, 0, stream>>>(delay, pi_w1, pi_b1, pi_w2, pi_b2, buf0);

    for (int l = 0; l < NLVL; l++) {
        float* pv = (l & 1) ? buf1 : buf0;
        float* nx = (l & 1) ? buf0 : buf1;
        level_kernel<<<NP / TN, 256, 0, stream>>>(
            pv, nx, feat, bitpos, srcidx,
            gate_w1, gate_b1, gate_w2, gate_b2,
            mod_w1, mod_b1, mod_w2, mod_b2,
            type_w1, type_b1, type_w2, type_b2,
            pos_w1, pos_b1, pos_w2, pos_b2,
            attn_vec, l, (l != NLVL - 1) ? 1 : 0);
    }

    final_kernel<<<NP / TN, 256, 0, stream>>>(
        buf1, pofeat,
        glob_w1, glob_b1, glob_w2, glob_b2,
        out_w1, out_b1, out_w2, out_b2,
        (float*)d_out);
}

// Round 5
// 967.661 us; speedup vs baseline: 6.2740x; 6.2740x over previous
//
#include <hip/hip_runtime.h>
#include <math.h>

#define HD   256
#define FIN  32
#define NP   8192
#define PGH  4096
#define NLVL 15
#define TN   16    // nodes per block tile

__device__ __forceinline__ float lrelu(float x) { return x > 0.f ? x : 0.1f * x; }

// cooperative stage: n4 float4s global->LDS, n4 MUST be a multiple of 1024.
// 4 named temps (16 VGPRs), 4 loads in flight, no arrays -> no scratch.
__device__ __forceinline__ void stage_w(const float* __restrict__ g, float* l, int n4, int tid)
{
    const float4* __restrict__ g4 = (const float4*)g;
    float4* l4 = (float4*)l;
    for (int base = 0; base < n4; base += 1024) {
        float4 ta = g4[base + tid];
        float4 tb = g4[base + tid + 256];
        float4 tc = g4[base + tid + 512];
        float4 td = g4[base + tid + 768];
        l4[base + tid]       = ta;
        l4[base + tid + 256] = tb;
        l4[base + tid + 512] = tc;
        l4[base + tid + 768] = td;
    }
}

// ---------------- pi kernel: prev_h = mlp(delay) ----------------
__global__ __launch_bounds__(256) void pi_kernel(
    const float* __restrict__ delay,
    const float* __restrict__ w1, const float* __restrict__ b1,
    const float* __restrict__ w2, const float* __restrict__ b2,
    float* __restrict__ outh)
{
    __shared__ float g1[TN][132];
    __shared__ float wbuf[32 * 256];
    const int tid = threadIdx.x;
    const int node0 = blockIdx.x * TN;

    for (int t = tid; t < TN * 128; t += 256) {
        int i = t >> 7, jj = t & 127;
        g1[i][jj] = lrelu(delay[node0 + i] * w1[jj] + b1[jj]);
    }

    const int j = (tid & 63) * 4;
    const int rg = (tid >> 6) * 4;
    float acc[4][4];
    float4 bv = *(const float4*)&b2[j];
#pragma unroll
    for (int ri = 0; ri < 4; ri++) { acc[ri][0] = bv.x; acc[ri][1] = bv.y; acc[ri][2] = bv.z; acc[ri][3] = bv.w; }

    for (int kc = 0; kc < 128; kc += 32) {
        __syncthreads();
        stage_w(w2 + (size_t)kc * 256, wbuf, 2048, tid);
        __syncthreads();
        for (int k = 0; k < 32; k += 4) {
            float4 x0 = *(const float4*)&g1[rg + 0][kc + k];
            float4 x1 = *(const float4*)&g1[rg + 1][kc + k];
            float4 x2v = *(const float4*)&g1[rg + 2][kc + k];
            float4 x3 = *(const float4*)&g1[rg + 3][kc + k];
#define PIK(comp, off) { float4 wv = *(const float4*)&wbuf[(k + off) * 256 + j]; \
    acc[0][0] += x0.comp * wv.x; acc[0][1] += x0.comp * wv.y; acc[0][2] += x0.comp * wv.z; acc[0][3] += x0.comp * wv.w; \
    acc[1][0] += x1.comp * wv.x; acc[1][1] += x1.comp * wv.y; acc[1][2] += x1.comp * wv.z; acc[1][3] += x1.comp * wv.w; \
    acc[2][0] += x2v.comp * wv.x; acc[2][1] += x2v.comp * wv.y; acc[2][2] += x2v.comp * wv.z; acc[2][3] += x2v.comp * wv.w; \
    acc[3][0] += x3.comp * wv.x; acc[3][1] += x3.comp * wv.y; acc[3][2] += x3.comp * wv.z; acc[3][3] += x3.comp * wv.w; }
            PIK(x, 0) PIK(y, 1) PIK(z, 2) PIK(w, 3)
#undef PIK
        }
    }
#pragma unroll
    for (int ri = 0; ri < 4; ri++)
        *(float4*)&outh[(node0 + rg + ri) * HD + j] =
            make_float4(acc[ri][0], acc[ri][1], acc[ri][2], acc[ri][3]);
}

// ---------------- per-level kernel: blocks 0..255 gate, 256..511 mod ----------------
__global__ __launch_bounds__(256) void level_kernel(
    const float* __restrict__ prevh, float* __restrict__ nexth,
    const float* __restrict__ feat, const float* __restrict__ bitpos,
    const int* __restrict__ srcidx,
    const float* __restrict__ g_w1, const float* __restrict__ g_b1,
    const float* __restrict__ g_w2, const float* __restrict__ g_b2,
    const float* __restrict__ m_w1, const float* __restrict__ m_b1,
    const float* __restrict__ m_w2, const float* __restrict__ m_b2,
    const float* __restrict__ t_w1, const float* __restrict__ t_b1,
    const float* __restrict__ t_w2, const float* __restrict__ t_b2,
    const float* __restrict__ p_w1, const float* __restrict__ p_b1,
    const float* __restrict__ p_w2, const float* __restrict__ p_b2,
    const float* __restrict__ av,
    int level, int apply_relu)
{
    __shared__ float x_lds[TN][292];
    __shared__ float h1_lds[TN][132];
    __shared__ float wbuf[64 * 128];     // 32 KB staging buffer
    __shared__ int   src_lds[TN * 8];
    __shared__ float bp_lds[TN * 8];
    __shared__ float dstf_lds[TN][32];
    __shared__ float ztt_lds[TN][32];
    __shared__ float smdot_lds[TN * 8];
    __shared__ float alpha_lds[TN * 8];
    __shared__ float xbp_lds[TN];
    __shared__ float av_lds[320];
    __shared__ float tw2av_lds[32];
    __shared__ float pw2av_lds[32];
    __shared__ float bias_av[2];

    const int tid = threadIdx.x;
    const bool is_gate = (blockIdx.x < 256);
    const int node0 = is_gate ? (blockIdx.x * TN) : (PGH + ((int)blockIdx.x - 256) * TN);

    if (tid < TN * 8) src_lds[tid] = srcidx[(level * NP + node0) * 8 + tid];

    if (is_gate) {
        for (int t = tid; t < TN * 32; t += 256) {
            int i = t >> 5, k = t & 31;
            x_lds[i][256 + k] = feat[((level + 1) * NP + node0 + i) * FIN + k];
        }
        __syncthreads();
        // gather + per-channel softmax over fanin, 2-node chunks (16 loads in flight)
        for (int s0 = 0; s0 < TN; s0 += 2) {
            const int* spA = &src_lds[s0 * 8];
            const int* spB = &src_lds[s0 * 8 + 8];
            float ma[8], mb[8];
#pragma unroll
            for (int f = 0; f < 8; f++) ma[f] = prevh[spA[f] * HD + tid];
#pragma unroll
            for (int f = 0; f < 8; f++) mb[f] = prevh[spB[f] * HD + tid];
            float mxa = -1e30f, mxb = -1e30f;
#pragma unroll
            for (int f = 0; f < 8; f++) { mxa = fmaxf(mxa, ma[f]); mxb = fmaxf(mxb, mb[f]); }
            float sa = 0.f, wsa = 0.f, sb = 0.f, wsb = 0.f;
#pragma unroll
            for (int f = 0; f < 8; f++) {
                float ea = __expf(ma[f] - mxa); sa += ea; wsa += ma[f] * ea;
                float eb = __expf(mb[f] - mxb); sb += eb; wsb += mb[f] * eb;
            }
            x_lds[s0][tid]     = wsa / sa;
            x_lds[s0 + 1][tid] = wsb / sb;
        }
        __syncthreads();
    } else {
        if (tid < TN * 8) bp_lds[tid] = bitpos[(level * NP + node0) * 8 + tid];
        for (int t = tid; t < TN * 32; t += 256) {
            int i = t >> 5, k = t & 31;
            dstf_lds[i][k] = feat[((level + 1) * NP + node0 + i) * FIN + k];
        }
        for (int t = tid; t < 320; t += 256) av_lds[t] = av[t];
        __syncthreads();

        // ztt = lrelu(dstf @ t_w1 + t_b1)
        for (int t = tid; t < TN * 32; t += 256) {
            int i = t >> 5, jj = t & 31;
            float a = t_b1[jj];
#pragma unroll 8
            for (int k = 0; k < 32; k++) a += dstf_lds[i][k] * t_w1[k * 32 + jj];
            ztt_lds[i][jj] = lrelu(a);
        }
        // fold attn_vec through second MLP layers (exact linear reassociation)
        if (tid < 32) {
            float s = 0.f;
#pragma unroll 8
            for (int jj = 0; jj < 32; jj++) s += t_w2[tid * 32 + jj] * av_lds[jj];
            tw2av_lds[tid] = s;
        } else if (tid < 64) {
            int k = tid - 32;
            float s = 0.f;
#pragma unroll 8
            for (int jj = 0; jj < 32; jj++) s += p_w2[k * 32 + jj] * av_lds[32 + jj];
            pw2av_lds[k] = s;
        } else if (tid == 64) {
            float s = 0.f;
#pragma unroll 8
            for (int jj = 0; jj < 32; jj++) s += t_b2[jj] * av_lds[jj];
            bias_av[0] = s;
        } else if (tid == 65) {
            float s = 0.f;
#pragma unroll 8
            for (int jj = 0; jj < 32; jj++) s += p_b2[jj] * av_lds[32 + jj];
            bias_av[1] = s;
        }
        // sm . av[64:320] per gathered row: 4 waves x 32 rows, 4-row chunks
        {
            const int wave = tid >> 6, lane = tid & 63;
            float4 av4 = *(const float4*)&av_lds[64 + lane * 4];
            for (int t0 = 0; t0 < 32; t0 += 4) {
                float4 xa = *(const float4*)&prevh[src_lds[wave + 4 * (t0 + 0)] * HD + lane * 4];
                float4 xb = *(const float4*)&prevh[src_lds[wave + 4 * (t0 + 1)] * HD + lane * 4];
                float4 xc = *(const float4*)&prevh[src_lds[wave + 4 * (t0 + 2)] * HD + lane * 4];
                float4 xd = *(const float4*)&prevh[src_lds[wave + 4 * (t0 + 3)] * HD + lane * 4];
                float pa = xa.x * av4.x + xa.y * av4.y + xa.z * av4.z + xa.w * av4.w;
                float pb = xb.x * av4.x + xb.y * av4.y + xb.z * av4.z + xb.w * av4.w;
                float pc = xc.x * av4.x + xc.y * av4.y + xc.z * av4.z + xc.w * av4.w;
                float pd = xd.x * av4.x + xd.y * av4.y + xd.z * av4.z + xd.w * av4.w;
#pragma unroll
                for (int off = 32; off > 0; off >>= 1) {
                    pa += __shfl_xor(pa, off); pb += __shfl_xor(pb, off);
                    pc += __shfl_xor(pc, off); pd += __shfl_xor(pd, off);
                }
                if (lane == 0) {
                    smdot_lds[wave + 4 * (t0 + 0)] = pa;
                    smdot_lds[wave + 4 * (t0 + 1)] = pb;
                    smdot_lds[wave + 4 * (t0 + 2)] = pc;
                    smdot_lds[wave + 4 * (t0 + 3)] = pd;
                }
            }
        }
        __syncthreads();

        // logits + softmax over fanin: tid = i*16 + f*2 + jg
        {
            const int jg = tid & 1, f = (tid >> 1) & 7, i = tid >> 4;
            const float bpv = bp_lds[i * 8 + f];
            float part = 0.f;
            const int k0 = jg * 16;
#pragma unroll
            for (int k = k0; k < k0 + 16; k++) {
                float h1pk = lrelu(bpv * p_w1[k] + p_b1[k]);
                part += h1pk * pw2av_lds[k];
                part += ztt_lds[i][k] * tw2av_lds[k];
            }
            part += __shfl_xor(part, 1);
            float logit = part + bias_av[0] + bias_av[1] + smdot_lds[i * 8 + f];
            float mx = logit;
            mx = fmaxf(mx, __shfl_xor(mx, 2));
            mx = fmaxf(mx, __shfl_xor(mx, 4));
            mx = fmaxf(mx, __shfl_xor(mx, 8));
            float e = __expf(logit - mx);
            float ssum = e;
            ssum += __shfl_xor(ssum, 2);
            ssum += __shfl_xor(ssum, 4);
            ssum += __shfl_xor(ssum, 8);
            float alpha = e / ssum;
            if (jg == 0) alpha_lds[i * 8 + f] = alpha;
            float ab = alpha * bpv;
            ab += __shfl_xor(ab, 2);
            ab += __shfl_xor(ab, 4);
            ab += __shfl_xor(ab, 8);
            if ((tid & 15) == 0) xbp_lds[i] = ab;
        }
        __syncthreads();

        // neigh_m, 2-node chunks + assemble x = [neigh_m(256), bp_sum, dstf(32)]
        for (int s0 = 0; s0 < TN; s0 += 2) {
            const int* spA = &src_lds[s0 * 8];
            const int* spB = &src_lds[s0 * 8 + 8];
            float ma[8], mb[8];
#pragma unroll
            for (int f = 0; f < 8; f++) ma[f] = prevh[spA[f] * HD + tid];
#pragma unroll
            for (int f = 0; f < 8; f++) mb[f] = prevh[spB[f] * HD + tid];
            const float* apA = &alpha_lds[s0 * 8];
            const float* apB = &alpha_lds[s0 * 8 + 8];
            float aa = 0.f, ab2 = 0.f;
#pragma unroll
            for (int f = 0; f < 8; f++) { aa += apA[f] * ma[f]; ab2 += apB[f] * mb[f]; }
            x_lds[s0][tid]     = aa;
            x_lds[s0 + 1][tid] = ab2;
        }
        if (tid < TN) x_lds[tid][256] = xbp_lds[tid];
        for (int t = tid; t < TN * 32; t += 256) {
            int i = t >> 5, k = t & 31;
            x_lds[i][257 + k] = dstf_lds[i][k];
        }
        __syncthreads();
    }

    // ---------- GEMM1: (TN x K1) @ (K1 x 128) + b1, leaky; weights LDS-staged ----------
    const float* w1 = is_gate ? g_w1 : m_w1;
    const float* b1 = is_gate ? g_b1 : m_b1;
    {
        const int j = (tid & 63) * 2;
        const int rg = (tid >> 6) * 4;
        float acc[4][2];
        float2 bv = *(const float2*)&b1[j];
#pragma unroll
        for (int ri = 0; ri < 4; ri++) { acc[ri][0] = bv.x; acc[ri][1] = bv.y; }

        for (int kc = 0; kc < 288; kc += 64) {
            const int KC = (288 - kc) < 64 ? (288 - kc) : 64;   // 64,64,64,64,32
            __syncthreads();
            stage_w(w1 + (size_t)kc * 128, wbuf, KC * 32, tid); // 2048 or 1024 float4s
            __syncthreads();
            for (int k = 0; k < KC; k += 4) {
                float4 x0 = *(const float4*)&x_lds[rg + 0][kc + k];
                float4 x1 = *(const float4*)&x_lds[rg + 1][kc + k];
                float4 x2v = *(const float4*)&x_lds[rg + 2][kc + k];
                float4 x3 = *(const float4*)&x_lds[rg + 3][kc + k];
#define G1K(comp, off) { float2 wv = *(const float2*)&wbuf[(k + off) * 128 + j]; \
    acc[0][0] += x0.comp * wv.x; acc[0][1] += x0.comp * wv.y; \
    acc[1][0] += x1.comp * wv.x; acc[1][1] += x1.comp * wv.y; \
    acc[2][0] += x2v.comp * wv.x; acc[2][1] += x2v.comp * wv.y; \
    acc[3][0] += x3.comp * wv.x; acc[3][1] += x3.comp * wv.y; }
                G1K(x, 0) G1K(y, 1) G1K(z, 2) G1K(w, 3)
#undef G1K
            }
        }
        if (!is_gate) {
            float2 wt = *(const float2*)&w1[288 * 128 + j];
#pragma unroll
            for (int ri = 0; ri < 4; ri++) {
                float xb = x_lds[rg + ri][288];
                acc[ri][0] += xb * wt.x; acc[ri][1] += xb * wt.y;
            }
        }
#pragma unroll
        for (int ri = 0; ri < 4; ri++)
            *(float2*)&h1_lds[rg + ri][j] = make_float2(lrelu(acc[ri][0]), lrelu(acc[ri][1]));
    }

    // ---------- GEMM2: (TN x 128) @ (128 x 256) + b2 (+relu); weights LDS-staged ----------
    const float* w2 = is_gate ? g_w2 : m_w2;
    const float* b2 = is_gate ? g_b2 : m_b2;
    {
        const int j = (tid & 63) * 4;
        const int rg = (tid >> 6) * 4;
        float acc[4][4];
        float4 bv = *(const float4*)&b2[j];
#pragma unroll
        for (int ri = 0; ri < 4; ri++) { acc[ri][0] = bv.x; acc[ri][1] = bv.y; acc[ri][2] = bv.z; acc[ri][3] = bv.w; }

        for (int kc = 0; kc < 128; kc += 32) {
            __syncthreads();
            stage_w(w2 + (size_t)kc * 256, wbuf, 2048, tid);
            __syncthreads();
            for (int k = 0; k < 32; k += 4) {
                float4 x0 = *(const float4*)&h1_lds[rg + 0][kc + k];
                float4 x1 = *(const float4*)&h1_lds[rg + 1][kc + k];
                float4 x2v = *(const float4*)&h1_lds[rg + 2][kc + k];
                float4 x3 = *(const float4*)&h1_lds[rg + 3][kc + k];
#define G2K(comp, off) { float4 wv = *(const float4*)&wbuf[(k + off) * 256 + j]; \
    acc[0][0] += x0.comp * wv.x; acc[0][1] += x0.comp * wv.y; acc[0][2] += x0.comp * wv.z; acc[0][3] += x0.comp * wv.w; \
    acc[1][0] += x1.comp * wv.x; acc[1][1] += x1.comp * wv.y; acc[1][2] += x1.comp * wv.z; acc[1][3] += x1.comp * wv.w; \
    acc[2][0] += x2v.comp * wv.x; acc[2][1] += x2v.comp * wv.y; acc[2][2] += x2v.comp * wv.z; acc[2][3] += x2v.comp * wv.w; \
    acc[3][0] += x3.comp * wv.x; acc[3][1] += x3.comp * wv.y; acc[3][2] += x3.comp * wv.z; acc[3][3] += x3.comp * wv.w; }
                G2K(x, 0) G2K(y, 1) G2K(z, 2) G2K(w, 3)
#undef G2K
            }
        }
#pragma unroll
        for (int ri = 0; ri < 4; ri++) {
            if (apply_relu) {
#pragma unroll
                for (int ci = 0; ci < 4; ci++) acc[ri][ci] = fmaxf(acc[ri][ci], 0.f);
            }
            *(float4*)&nexth[(node0 + rg + ri) * HD + j] =
                make_float4(acc[ri][0], acc[ri][1], acc[ri][2], acc[ri][3]);
        }
    }
}

// ---------------- final kernel: glob mlp + concat + out mlp (fused) ----------------
__global__ __launch_bounds__(256) void final_kernel(
    const float* __restrict__ prevh, const float* __restrict__ pofeat,
    const float* __restrict__ gl_w1, const float* __restrict__ gl_b1,
    const float* __restrict__ gl_w2, const float* __restrict__ gl_b2,
    const float* __restrict__ o_w1, const float* __restrict__ o_b1,
    const float* __restrict__ o_w2, const float* __restrict__ o_b2,
    float* __restrict__ out)
{
    __shared__ float x2[TN][516];
    __shared__ float g1[TN][132];
    __shared__ float wbuf[32 * 256];
    __shared__ float ow2_lds[256];

    const int tid = threadIdx.x;
    const int node0 = blockIdx.x * TN;
    const int j = (tid & 63) * 4;
    const int rg = (tid >> 6) * 4;

    for (int q = tid; q < TN * 64; q += 256) {
        int i = q >> 6, c4 = (q & 63) * 4;
        *(float4*)&x2[i][c4] = *(const float4*)&prevh[(node0 + i) * HD + c4];
    }
    for (int t = tid; t < TN * 128; t += 256) {
        int i = t >> 7, jj = t & 127;
        g1[i][jj] = lrelu(pofeat[node0 + i] * gl_w1[jj] + gl_b1[jj]);
    }
    ow2_lds[tid] = o_w2[tid];

    // glob layer 2: (TN x 128)@(128 x 256) -> x2 cols 256..511, staged
    {
        float acc[4][4];
        float4 bv = *(const float4*)&gl_b2[j];
#pragma unroll
        for (int ri = 0; ri < 4; ri++) { acc[ri][0] = bv.x; acc[ri][1] = bv.y; acc[ri][2] = bv.z; acc[ri][3] = bv.w; }
        for (int kc = 0; kc < 128; kc += 32) {
            __syncthreads();
            stage_w(gl_w2 + (size_t)kc * 256, wbuf, 2048, tid);
            __syncthreads();
            for (int k = 0; k < 32; k += 4) {
                float4 x0 = *(const float4*)&g1[rg + 0][kc + k];
                float4 x1 = *(const float4*)&g1[rg + 1][kc + k];
                float4 x2v = *(const float4*)&g1[rg + 2][kc + k];
                float4 x3 = *(const float4*)&g1[rg + 3][kc + k];
#define GLK(comp, off) { float4 wv = *(const float4*)&wbuf[(k + off) * 256 + j]; \
    acc[0][0] += x0.comp * wv.x; acc[0][1] += x0.comp * wv.y; acc[0][2] += x0.comp * wv.z; acc[0][3] += x0.comp * wv.w; \
    acc[1][0] += x1.comp * wv.x; acc[1][1] += x1.comp * wv.y; acc[1][2] += x1.comp * wv.z; acc[1][3] += x1.comp * wv.w; \
    acc[2][0] += x2v.comp * wv.x; acc[2][1] += x2v.comp * wv.y; acc[2][2] += x2v.comp * wv.z; acc[2][3] += x2v.comp * wv.w; \
    acc[3][0] += x3.comp * wv.x; acc[3][1] += x3.comp * wv.y; acc[3][2] += x3.comp * wv.z; acc[3][3] += x3.comp * wv.w; }
                GLK(x, 0) GLK(y, 1) GLK(z, 2) GLK(w, 3)
#undef GLK
            }
        }
#pragma unroll
        for (int ri = 0; ri < 4; ri++)
            *(float4*)&x2[rg + ri][256 + j] = make_float4(acc[ri][0], acc[ri][1], acc[ri][2], acc[ri][3]);
    }
    __syncthreads();

    // out layer 1 (staged) fused with out layer 2 (wave reduction)
    {
        float acc[4][4];
        float4 bv = *(const float4*)&o_b1[j];
#pragma unroll
        for (int ri = 0; ri < 4; ri++) { acc[ri][0] = bv.x; acc[ri][1] = bv.y; acc[ri][2] = bv.z; acc[ri][3] = bv.w; }
        for (int kc = 0; kc < 512; kc += 32) {
            __syncthreads();
            stage_w(o_w1 + (size_t)kc * 256, wbuf, 2048, tid);
            __syncthreads();
            for (int k = 0; k < 32; k += 4) {
                float4 x0 = *(const float4*)&x2[rg + 0][kc + k];
                float4 x1 = *(const float4*)&x2[rg + 1][kc + k];
                float4 x2v = *(const float4*)&x2[rg + 2][kc + k];
                float4 x3 = *(const float4*)&x2[rg + 3][kc + k];
#define O1K(comp, off) { float4 wv = *(const float4*)&wbuf[(k + off) * 256 + j]; \
    acc[0][0] += x0.comp * wv.x; acc[0][1] += x0.comp * wv.y; acc[0][2] += x0.comp * wv.z; acc[0][3] += x0.comp * wv.w; \
    acc[1][0] += x1.comp * wv.x; acc[1][1] += x1.comp * wv.y; acc[1][2] += x1.comp * wv.z; acc[1][3] += x1.comp * wv.w; \
    acc[2][0] += x2v.comp * wv.x; acc[2][1] += x2v.comp * wv.y; acc[2][2] += x2v.comp * wv.z; acc[2][3] += x2v.comp * wv.w; \
    acc[3][0] += x3.comp * wv.x; acc[3][1] += x3.comp * wv.y; acc[3][2] += x3.comp * wv.z; acc[3][3] += x3.comp * wv.w; }
                O1K(x, 0) O1K(y, 1) O1K(z, 2) O1K(w, 3)
#undef O1K
            }
        }
        // out layer 2: each wave reduces its 4 rows over cols j..j+3
        float4 wv = *(const float4*)&ow2_lds[j];
        float ob = o_b2[0];
#pragma unroll
        for (int ri = 0; ri < 4; ri++) {
            float p = lrelu(acc[ri][0]) * wv.x + lrelu(acc[ri][1]) * wv.y
                    + lrelu(acc[ri][2]) * wv.z + lrelu(acc[ri][3]) * wv.w;
#pragma unroll
            for (int off = 1; off < 64; off <<= 1) p += __shfl_xor(p, off);
            if ((tid & 63) == 0) out[node0 + rg + ri] = p + ob;
        }
    }
}

extern "C" void kernel_launch(void* const* d_in, const int* in_sizes, int n_in,
                              void* d_out, int out_size, void* d_ws, size_t ws_size,
                              hipStream_t stream)
{
    const float* delay    = (const float*)d_in[0];
    const float* feat     = (const float*)d_in[1];
    const float* bitpos   = (const float*)d_in[2];
    const float* pofeat   = (const float*)d_in[3];
    const int*   srcidx   = (const int*)  d_in[4];
    const float* pi_w1    = (const float*)d_in[5];
    const float* pi_b1    = (const float*)d_in[6];
    const float* pi_w2    = (const float*)d_in[7];
    const float* pi_b2    = (const float*)d_in[8];
    const float* gate_w1  = (const float*)d_in[9];
    const float* gate_b1  = (const float*)d_in[10];
    const float* gate_w2  = (const float*)d_in[11];
    const float* gate_b2  = (const float*)d_in[12];
    const float* mod_w1   = (const float*)d_in[13];
    const float* mod_b1   = (const float*)d_in[14];
    const float* mod_w2   = (const float*)d_in[15];
    const float* mod_b2   = (const float*)d_in[16];
    const float* type_w1  = (const float*)d_in[17];
    const float* type_b1  = (const float*)d_in[18];
    const float* type_w2  = (const float*)d_in[19];
    const float* type_b2  = (const float*)d_in[20];
    const float* pos_w1   = (const float*)d_in[21];
    const float* pos_b1   = (const float*)d_in[22];
    const float* pos_w2   = (const float*)d_in[23];
    const float* pos_b2   = (const float*)d_in[24];
    const float* attn_vec = (const float*)d_in[25];
    const float* glob_w1  = (const float*)d_in[26];
    const float* glob_b1  = (const float*)d_in[27];
    const float* glob_w2  = (const float*)d_in[28];
    const float* glob_b2  = (const float*)d_in[29];
    const float* out_w1   = (const float*)d_in[30];
    const float* out_b1   = (const float*)d_in[31];
    const float* out_w2   = (const float*)d_in[32];
    const float* out_b2   = (const float*)d_in[33];

    float* buf0 = (float*)d_ws;
    float* buf1 = buf0 + (size_t)NP * HD;

    pi_kernel<<<NP / TN, 256, 0, stream>>>(delay, pi_w1, pi_b1, pi_w2, pi_b2, buf0);

    for (int l = 0; l < NLVL; l++) {
        float* pv = (l & 1) ? buf1 : buf0;
        float* nx = (l & 1) ? buf0 : buf1;
        level_kernel<<<NP / TN, 256, 0, stream>>>(
            pv, nx, feat, bitpos, srcidx,
            gate_w1, gate_b1, gate_w2, gate_b2,
            mod_w1, mod_b1, mod_w2, mod_b2,
            type_w1, type_b1, type_w2, type_b2,
            pos_w1, pos_b1, pos_w2, pos_b2,
            attn_vec, l, (l != NLVL - 1) ? 1 : 0);
    }

    final_kernel<<<NP / TN, 256, 0, stream>>>(
        buf1, pofeat,
        glob_w1, glob_b1, glob_w2, glob_b2,
        out_w1, out_b1, out_w2, out_b2,
        (float*)d_out);
}

// Round 6
// 961.486 us; speedup vs baseline: 6.3143x; 1.0064x over previous
//
#include <hip/hip_runtime.h>
#include <math.h>

#define HD   256
#define FIN  32
#define NP   8192
#define PGH  4096
#define NLVL 15
#define TN   16    // nodes per block tile

__device__ __forceinline__ float lrelu(float x) { return x > 0.f ? x : 0.1f * x; }

// ---------------- pi kernel: prev_h = mlp(delay) ----------------
__global__ __launch_bounds__(512, 4) void pi_kernel(
    const float* __restrict__ delay,
    const float* __restrict__ w1, const float* __restrict__ b1,
    const float* __restrict__ w2, const float* __restrict__ b2,
    float* __restrict__ outh)
{
    __shared__ float g1[TN][132];
    const int tid = threadIdx.x;
    const int node0 = blockIdx.x * TN;

    for (int t = tid; t < TN * 128; t += 512) {
        int i = t >> 7, jj = t & 127;
        g1[i][jj] = lrelu(delay[node0 + i] * w1[jj] + b1[jj]);
    }
    __syncthreads();

    const int j = (tid & 63) * 4;
    const int rg = (tid >> 6) * 2;
    float acc[2][4];
    float4 bv = *(const float4*)&b2[j];
#pragma unroll
    for (int ri = 0; ri < 2; ri++) { acc[ri][0] = bv.x; acc[ri][1] = bv.y; acc[ri][2] = bv.z; acc[ri][3] = bv.w; }

#pragma unroll 4
    for (int k = 0; k < 128; k += 4) {
        float4 x0 = *(const float4*)&g1[rg + 0][k];
        float4 x1 = *(const float4*)&g1[rg + 1][k];
        const float* wp = w2 + (size_t)k * 256 + j;
#define PIK(comp, off) { float4 wv = *(const float4*)(wp + (off) * 256); \
    acc[0][0] += x0.comp * wv.x; acc[0][1] += x0.comp * wv.y; acc[0][2] += x0.comp * wv.z; acc[0][3] += x0.comp * wv.w; \
    acc[1][0] += x1.comp * wv.x; acc[1][1] += x1.comp * wv.y; acc[1][2] += x1.comp * wv.z; acc[1][3] += x1.comp * wv.w; }
        PIK(x, 0) PIK(y, 1) PIK(z, 2) PIK(w, 3)
#undef PIK
    }
#pragma unroll
    for (int ri = 0; ri < 2; ri++)
        *(float4*)&outh[(node0 + rg + ri) * HD + j] =
            make_float4(acc[ri][0], acc[ri][1], acc[ri][2], acc[ri][3]);
}

// ---------------- per-level kernel: blocks 0..255 gate, 256..511 mod ----------------
__global__ __launch_bounds__(512, 4) void level_kernel(
    const float* __restrict__ prevh, float* __restrict__ nexth,
    const float* __restrict__ feat, const float* __restrict__ bitpos,
    const int* __restrict__ srcidx,
    const float* __restrict__ g_w1, const float* __restrict__ g_b1,
    const float* __restrict__ g_w2, const float* __restrict__ g_b2,
    const float* __restrict__ m_w1, const float* __restrict__ m_b1,
    const float* __restrict__ m_w2, const float* __restrict__ m_b2,
    const float* __restrict__ t_w1, const float* __restrict__ t_b1,
    const float* __restrict__ t_w2, const float* __restrict__ t_b2,
    const float* __restrict__ p_w1, const float* __restrict__ p_b1,
    const float* __restrict__ p_w2, const float* __restrict__ p_b2,
    const float* __restrict__ av,
    int level, int apply_relu)
{
    __shared__ float x_lds[TN][292];
    __shared__ float h1_lds[TN][132];
    __shared__ int   src_lds[TN * 8];
    __shared__ float bp_lds[TN * 8];
    __shared__ float dstf_lds[TN][32];
    __shared__ float ztt_lds[TN][32];
    __shared__ float smdot_lds[TN * 8];
    __shared__ float alpha_lds[TN * 8];
    __shared__ float xbp_lds[TN];
    __shared__ float av_lds[320];
    __shared__ float tw2av_lds[32];
    __shared__ float pw2av_lds[32];
    __shared__ float bias_av[2];

    const int tid = threadIdx.x;
    const bool is_gate = (blockIdx.x < 256);
    const int node0 = is_gate ? (blockIdx.x * TN) : (PGH + ((int)blockIdx.x - 256) * TN);

    if (tid < TN * 8) src_lds[tid] = srcidx[(level * NP + node0) * 8 + tid];

    if (is_gate) {
        if (tid < TN * 32) {
            int i = tid >> 5, k = tid & 31;
            x_lds[i][256 + k] = feat[((level + 1) * NP + node0 + i) * FIN + k];
        }
        __syncthreads();
        // gather + per-channel softmax over fanin: thread = (half, channel), 2-node chunks
        {
            const int c = tid & 255, sh = (tid >> 8) * 8;
            for (int s0 = 0; s0 < 8; s0 += 2) {
                const int* spA = &src_lds[(sh + s0) * 8];
                const int* spB = &src_lds[(sh + s0 + 1) * 8];
                float ma[8], mb[8];
#pragma unroll
                for (int f = 0; f < 8; f++) ma[f] = prevh[spA[f] * HD + c];
#pragma unroll
                for (int f = 0; f < 8; f++) mb[f] = prevh[spB[f] * HD + c];
                float mxa = -1e30f, mxb = -1e30f;
#pragma unroll
                for (int f = 0; f < 8; f++) { mxa = fmaxf(mxa, ma[f]); mxb = fmaxf(mxb, mb[f]); }
                float sa = 0.f, wsa = 0.f, sb = 0.f, wsb = 0.f;
#pragma unroll
                for (int f = 0; f < 8; f++) {
                    float ea = __expf(ma[f] - mxa); sa += ea; wsa += ma[f] * ea;
                    float eb = __expf(mb[f] - mxb); sb += eb; wsb += mb[f] * eb;
                }
                x_lds[sh + s0][c]     = wsa / sa;
                x_lds[sh + s0 + 1][c] = wsb / sb;
            }
        }
        __syncthreads();
    } else {
        if (tid < TN * 8) bp_lds[tid] = bitpos[(level * NP + node0) * 8 + tid];
        if (tid < 320) av_lds[tid] = av[tid];
        {
            int i = tid >> 5, k = tid & 31;
            dstf_lds[i][k] = feat[((level + 1) * NP + node0 + i) * FIN + k];
        }
        __syncthreads();

        // ztt = lrelu(dstf @ t_w1 + t_b1): one output per thread (512 = 16*32)
        {
            int i = tid >> 5, jj = tid & 31;
            float a = t_b1[jj];
#pragma unroll 8
            for (int k = 0; k < 32; k++) a += dstf_lds[i][k] * t_w1[k * 32 + jj];
            ztt_lds[i][jj] = lrelu(a);
        }
        // fold attn_vec through second MLP layers (exact linear reassociation)
        if (tid < 32) {
            float s = 0.f;
#pragma unroll 8
            for (int jj = 0; jj < 32; jj++) s += t_w2[tid * 32 + jj] * av_lds[jj];
            tw2av_lds[tid] = s;
        } else if (tid < 64) {
            int k = tid - 32;
            float s = 0.f;
#pragma unroll 8
            for (int jj = 0; jj < 32; jj++) s += p_w2[k * 32 + jj] * av_lds[32 + jj];
            pw2av_lds[k] = s;
        } else if (tid == 64) {
            float s = 0.f;
#pragma unroll 8
            for (int jj = 0; jj < 32; jj++) s += t_b2[jj] * av_lds[jj];
            bias_av[0] = s;
        } else if (tid == 65) {
            float s = 0.f;
#pragma unroll 8
            for (int jj = 0; jj < 32; jj++) s += p_b2[jj] * av_lds[32 + jj];
            bias_av[1] = s;
        }
        // sm . av[64:320] per gathered row: 8 waves x 16 rows, 4-row chunks
        {
            const int wave = tid >> 6, lane = tid & 63;
            float4 av4 = *(const float4*)&av_lds[64 + lane * 4];
            for (int t0 = 0; t0 < 16; t0 += 4) {
                float4 xa = *(const float4*)&prevh[src_lds[wave + 8 * (t0 + 0)] * HD + lane * 4];
                float4 xb = *(const float4*)&prevh[src_lds[wave + 8 * (t0 + 1)] * HD + lane * 4];
                float4 xc = *(const float4*)&prevh[src_lds[wave + 8 * (t0 + 2)] * HD + lane * 4];
                float4 xd = *(const float4*)&prevh[src_lds[wave + 8 * (t0 + 3)] * HD + lane * 4];
                float pa = xa.x * av4.x + xa.y * av4.y + xa.z * av4.z + xa.w * av4.w;
                float pb = xb.x * av4.x + xb.y * av4.y + xb.z * av4.z + xb.w * av4.w;
                float pc = xc.x * av4.x + xc.y * av4.y + xc.z * av4.z + xc.w * av4.w;
                float pd = xd.x * av4.x + xd.y * av4.y + xd.z * av4.z + xd.w * av4.w;
#pragma unroll
                for (int off = 32; off > 0; off >>= 1) {
                    pa += __shfl_xor(pa, off); pb += __shfl_xor(pb, off);
                    pc += __shfl_xor(pc, off); pd += __shfl_xor(pd, off);
                }
                if (lane == 0) {
                    smdot_lds[wave + 8 * (t0 + 0)] = pa;
                    smdot_lds[wave + 8 * (t0 + 1)] = pb;
                    smdot_lds[wave + 8 * (t0 + 2)] = pc;
                    smdot_lds[wave + 8 * (t0 + 3)] = pd;
                }
            }
        }
        __syncthreads();

        // logits + softmax over fanin: first 256 threads, tid = i*16 + f*2 + jg
        if (tid < 256) {
            const int jg = tid & 1, f = (tid >> 1) & 7, i = tid >> 4;
            const float bpv = bp_lds[i * 8 + f];
            float part = 0.f;
            const int k0 = jg * 16;
#pragma unroll
            for (int k = k0; k < k0 + 16; k++) {
                float h1pk = lrelu(bpv * p_w1[k] + p_b1[k]);
                part += h1pk * pw2av_lds[k];
                part += ztt_lds[i][k] * tw2av_lds[k];
            }
            part += __shfl_xor(part, 1);
            float logit = part + bias_av[0] + bias_av[1] + smdot_lds[i * 8 + f];
            float mx = logit;
            mx = fmaxf(mx, __shfl_xor(mx, 2));
            mx = fmaxf(mx, __shfl_xor(mx, 4));
            mx = fmaxf(mx, __shfl_xor(mx, 8));
            float e = __expf(logit - mx);
            float ssum = e;
            ssum += __shfl_xor(ssum, 2);
            ssum += __shfl_xor(ssum, 4);
            ssum += __shfl_xor(ssum, 8);
            float alpha = e / ssum;
            if (jg == 0) alpha_lds[i * 8 + f] = alpha;
            float ab = alpha * bpv;
            ab += __shfl_xor(ab, 2);
            ab += __shfl_xor(ab, 4);
            ab += __shfl_xor(ab, 8);
            if ((tid & 15) == 0) xbp_lds[i] = ab;
        }
        __syncthreads();

        // neigh_m: thread = (half, channel), 2-node chunks; assemble x
        {
            const int c = tid & 255, sh = (tid >> 8) * 8;
            for (int s0 = 0; s0 < 8; s0 += 2) {
                const int* spA = &src_lds[(sh + s0) * 8];
                const int* spB = &src_lds[(sh + s0 + 1) * 8];
                float ma[8], mb[8];
#pragma unroll
                for (int f = 0; f < 8; f++) ma[f] = prevh[spA[f] * HD + c];
#pragma unroll
                for (int f = 0; f < 8; f++) mb[f] = prevh[spB[f] * HD + c];
                const float* apA = &alpha_lds[(sh + s0) * 8];
                const float* apB = &alpha_lds[(sh + s0) * 8 + 8];
                float aa = 0.f, ab2 = 0.f;
#pragma unroll
                for (int f = 0; f < 8; f++) { aa += apA[f] * ma[f]; ab2 += apB[f] * mb[f]; }
                x_lds[sh + s0][c]     = aa;
                x_lds[sh + s0 + 1][c] = ab2;
            }
        }
        if (tid < TN) x_lds[tid][256] = xbp_lds[tid];
        if (tid < TN * 32) {
            int i = tid >> 5, k = tid & 31;
            x_lds[i][257 + k] = dstf_lds[i][k];
        }
        __syncthreads();
    }

    // ---------- GEMM1: (TN x K1) @ (K1 x 128) + b1, leaky; weights streamed from L2 ----------
    const float* w1 = is_gate ? g_w1 : m_w1;
    const float* b1 = is_gate ? g_b1 : m_b1;
    {
        const int j = (tid & 63) * 2;
        const int rg = (tid >> 6) * 2;
        float acc[2][2];
        float2 bv = *(const float2*)&b1[j];
#pragma unroll
        for (int ri = 0; ri < 2; ri++) { acc[ri][0] = bv.x; acc[ri][1] = bv.y; }
#pragma unroll 4
        for (int k = 0; k < 288; k += 4) {
            float4 x0 = *(const float4*)&x_lds[rg + 0][k];
            float4 x1 = *(const float4*)&x_lds[rg + 1][k];
            const float* wp = w1 + (size_t)k * 128 + j;
#define G1K(comp, off) { float2 wv = *(const float2*)(wp + (off) * 128); \
    acc[0][0] += x0.comp * wv.x; acc[0][1] += x0.comp * wv.y; \
    acc[1][0] += x1.comp * wv.x; acc[1][1] += x1.comp * wv.y; }
            G1K(x, 0) G1K(y, 1) G1K(z, 2) G1K(w, 3)
#undef G1K
        }
        if (!is_gate) {
            float2 wt = *(const float2*)&w1[288 * 128 + j];
#pragma unroll
            for (int ri = 0; ri < 2; ri++) {
                float xb = x_lds[rg + ri][288];
                acc[ri][0] += xb * wt.x; acc[ri][1] += xb * wt.y;
            }
        }
#pragma unroll
        for (int ri = 0; ri < 2; ri++)
            *(float2*)&h1_lds[rg + ri][j] = make_float2(lrelu(acc[ri][0]), lrelu(acc[ri][1]));
    }
    __syncthreads();

    // ---------- GEMM2: (TN x 128) @ (128 x 256) + b2 (+relu); weights streamed ----------
    const float* w2 = is_gate ? g_w2 : m_w2;
    const float* b2 = is_gate ? g_b2 : m_b2;
    {
        const int j = (tid & 63) * 4;
        const int rg = (tid >> 6) * 2;
        float acc[2][4];
        float4 bv = *(const float4*)&b2[j];
#pragma unroll
        for (int ri = 0; ri < 2; ri++) { acc[ri][0] = bv.x; acc[ri][1] = bv.y; acc[ri][2] = bv.z; acc[ri][3] = bv.w; }
#pragma unroll 4
        for (int k = 0; k < 128; k += 4) {
            float4 x0 = *(const float4*)&h1_lds[rg + 0][k];
            float4 x1 = *(const float4*)&h1_lds[rg + 1][k];
            const float* wp = w2 + (size_t)k * 256 + j;
#define G2K(comp, off) { float4 wv = *(const float4*)(wp + (off) * 256); \
    acc[0][0] += x0.comp * wv.x; acc[0][1] += x0.comp * wv.y; acc[0][2] += x0.comp * wv.z; acc[0][3] += x0.comp * wv.w; \
    acc[1][0] += x1.comp * wv.x; acc[1][1] += x1.comp * wv.y; acc[1][2] += x1.comp * wv.z; acc[1][3] += x1.comp * wv.w; }
            G2K(x, 0) G2K(y, 1) G2K(z, 2) G2K(w, 3)
#undef G2K
        }
#pragma unroll
        for (int ri = 0; ri < 2; ri++) {
            if (apply_relu) {
#pragma unroll
                for (int ci = 0; ci < 4; ci++) acc[ri][ci] = fmaxf(acc[ri][ci], 0.f);
            }
            *(float4*)&nexth[(node0 + rg + ri) * HD + j] =
                make_float4(acc[ri][0], acc[ri][1], acc[ri][2], acc[ri][3]);
        }
    }
}

// ---------------- final kernel: glob mlp + concat + out mlp (fused) ----------------
__global__ __launch_bounds__(512, 4) void final_kernel(
    const float* __restrict__ prevh, const float* __restrict__ pofeat,
    const float* __restrict__ gl_w1, const float* __restrict__ gl_b1,
    const float* __restrict__ gl_w2, const float* __restrict__ gl_b2,
    const float* __restrict__ o_w1, const float* __restrict__ o_b1,
    const float* __restrict__ o_w2, const float* __restrict__ o_b2,
    float* __restrict__ out)
{
    __shared__ float x2[TN][516];
    __shared__ float g1[TN][132];
    __shared__ float ow2_lds[256];

    const int tid = threadIdx.x;
    const int node0 = blockIdx.x * TN;
    const int j = (tid & 63) * 4;
    const int rg = (tid >> 6) * 2;

    for (int q = tid; q < TN * 64; q += 512) {
        int i = q >> 6, c4 = (q & 63) * 4;
        *(float4*)&x2[i][c4] = *(const float4*)&prevh[(node0 + i) * HD + c4];
    }
    for (int t = tid; t < TN * 128; t += 512) {
        int i = t >> 7, jj = t & 127;
        g1[i][jj] = lrelu(pofeat[node0 + i] * gl_w1[jj] + gl_b1[jj]);
    }
    if (tid < 256) ow2_lds[tid] = o_w2[tid];
    __syncthreads();

    // glob layer 2: (TN x 128)@(128 x 256) -> x2 cols 256..511
    {
        float acc[2][4];
        float4 bv = *(const float4*)&gl_b2[j];
#pragma unroll
        for (int ri = 0; ri < 2; ri++) { acc[ri][0] = bv.x; acc[ri][1] = bv.y; acc[ri][2] = bv.z; acc[ri][3] = bv.w; }
#pragma unroll 4
        for (int k = 0; k < 128; k += 4) {
            float4 x0 = *(const float4*)&g1[rg + 0][k];
            float4 x1 = *(const float4*)&g1[rg + 1][k];
            const float* wp = gl_w2 + (size_t)k * 256 + j;
#define GLK(comp, off) { float4 wv = *(const float4*)(wp + (off) * 256); \
    acc[0][0] += x0.comp * wv.x; acc[0][1] += x0.comp * wv.y; acc[0][2] += x0.comp * wv.z; acc[0][3] += x0.comp * wv.w; \
    acc[1][0] += x1.comp * wv.x; acc[1][1] += x1.comp * wv.y; acc[1][2] += x1.comp * wv.z; acc[1][3] += x1.comp * wv.w; }
            GLK(x, 0) GLK(y, 1) GLK(z, 2) GLK(w, 3)
#undef GLK
        }
#pragma unroll
        for (int ri = 0; ri < 2; ri++)
            *(float4*)&x2[rg + ri][256 + j] = make_float4(acc[ri][0], acc[ri][1], acc[ri][2], acc[ri][3]);
    }
    __syncthreads();

    // out layer 1 (streamed) fused with out layer 2 (wave reduction)
    {
        float acc[2][4];
        float4 bv = *(const float4*)&o_b1[j];
#pragma unroll
        for (int ri = 0; ri < 2; ri++) { acc[ri][0] = bv.x; acc[ri][1] = bv.y; acc[ri][2] = bv.z; acc[ri][3] = bv.w; }
#pragma unroll 4
        for (int k = 0; k < 512; k += 4) {
            float4 x0 = *(const float4*)&x2[rg + 0][k];
            float4 x1 = *(const float4*)&x2[rg + 1][k];
            const float* wp = o_w1 + (size_t)k * 256 + j;
#define O1K(comp, off) { float4 wv = *(const float4*)(wp + (off) * 256); \
    acc[0][0] += x0.comp * wv.x; acc[0][1] += x0.comp * wv.y; acc[0][2] += x0.comp * wv.z; acc[0][3] += x0.comp * wv.w; \
    acc[1][0] += x1.comp * wv.x; acc[1][1] += x1.comp * wv.y; acc[1][2] += x1.comp * wv.z; acc[1][3] += x1.comp * wv.w; }
            O1K(x, 0) O1K(y, 1) O1K(z, 2) O1K(w, 3)
#undef O1K
        }
        // out layer 2: each wave's 64 lanes cover cols 0..255 for rows rg, rg+1
        float4 wv = *(const float4*)&ow2_lds[j];
        float ob = o_b2[0];
#pragma unroll
        for (int ri = 0; ri < 2; ri++) {
            float p = lrelu(acc[ri][0]) * wv.x + lrelu(acc[ri][1]) * wv.y
                    + lrelu(acc[ri][2]) * wv.z + lrelu(acc[ri][3]) * wv.w;
#pragma unroll
            for (int off = 1; off < 64; off <<= 1) p += __shfl_xor(p, off);
            if ((tid & 63) == 0) out[node0 + rg + ri] = p + ob;
        }
    }
}

extern "C" void kernel_launch(void* const* d_in, const int* in_sizes, int n_in,
                              void* d_out, int out_size, void* d_ws, size_t ws_size,
                              hipStream_t stream)
{
    const float* delay    = (const float*)d_in[0];
    const float* feat     = (const float*)d_in[1];
    const float* bitpos   = (const float*)d_in[2];
    const float* pofeat   = (const float*)d_in[3];
    const int*   srcidx   = (const int*)  d_in[4];
    const float* pi_w1    = (const float*)d_in[5];
    const float* pi_b1    = (const float*)d_in[6];
    const float* pi_w2    = (const float*)d_in[7];
    const float* pi_b2    = (const float*)d_in[8];
    const float* gate_w1  = (const float*)d_in[9];
    const float* gate_b1  = (const float*)d_in[10];
    const float* gate_w2  = (const float*)d_in[11];
    const float* gate_b2  = (const float*)d_in[12];
    const float* mod_w1   = (const float*)d_in[13];
    const float* mod_b1   = (const float*)d_in[14];
    const float* mod_w2   = (const float*)d_in[15];
    const float* mod_b2   = (const float*)d_in[16];
    const float* type_w1  = (const float*)d_in[17];
    const float* type_b1  = (const float*)d_in[18];
    const float* type_w2  = (const float*)d_in[19];
    const float* type_b2  = (const float*)d_in[20];
    const float* pos_w1   = (const float*)d_in[21];
    const float* pos_b1   = (const float*)d_in[22];
    const float* pos_w2   = (const float*)d_in[23];
    const float* pos_b2   = (const float*)d_in[24];
    const float* attn_vec = (const float*)d_in[25];
    const float* glob_w1  = (const float*)d_in[26];
    const float* glob_b1  = (const float*)d_in[27];
    const float* glob_w2  = (const float*)d_in[28];
    const float* glob_b2  = (const float*)d_in[29];
    const float* out_w1   = (const float*)d_in[30];
    const float* out_b1   = (const float*)d_in[31];
    const float* out_w2   = (const float*)d_in[32];
    const float* out_b2   = (const float*)d_in[33];

    float* buf0 = (float*)d_ws;
    float* buf1 = buf0 + (size_t)NP * HD;

    pi_kernel<<<NP / TN, 512, 0, stream>>>(delay, pi_w1, pi_b1, pi_w2, pi_b2, buf0);

    for (int l = 0; l < NLVL; l++) {
        float* pv = (l & 1) ? buf1 : buf0;
        float* nx = (l & 1) ? buf0 : buf1;
        level_kernel<<<NP / TN, 512, 0, stream>>>(
            pv, nx, feat, bitpos, srcidx,
            gate_w1, gate_b1, gate_w2, gate_b2,
            mod_w1, mod_b1, mod_w2, mod_b2,
            type_w1, type_b1, type_w2, type_b2,
            pos_w1, pos_b1, pos_w2, pos_b2,
            attn_vec, l, (l != NLVL - 1) ? 1 : 0);
    }

    final_kernel<<<NP / TN, 512, 0, stream>>>(
        buf1, pofeat,
        glob_w1, glob_b1, glob_w2, glob_b2,
        out_w1, out_b1, out_w2, out_b2,
        (float*)d_out);
}

// Round 8
// 671.303 us; speedup vs baseline: 9.0438x; 1.4323x over previous
//
#include <hip/hip_runtime.h>
#include <math.h>

#define HD   256
#define FIN  32
#define NP   8192
#define PGH  4096
#define NLVL 15
#define TN   16    // nodes per block tile

__device__ __forceinline__ float lrelu(float x) { return x > 0.f ? x : 0.1f * x; }

// ---------------- pi kernel: prev_h = mlp(delay) ----------------
__global__ __launch_bounds__(256) void pi_kernel(
    const float* __restrict__ delay,
    const float* __restrict__ w1, const float* __restrict__ b1,
    const float* __restrict__ w2, const float* __restrict__ b2,
    float* __restrict__ outh)
{
    __shared__ float g1[TN][132];
    const int tid = threadIdx.x;
    const int node0 = blockIdx.x * TN;

    for (int t = tid; t < TN * 128; t += 256) {
        int i = t >> 7, jj = t & 127;
        g1[i][jj] = lrelu(delay[node0 + i] * w1[jj] + b1[jj]);
    }
    __syncthreads();

    const int j = (tid & 63) * 4;
    const int rg = (tid >> 6) * 4;
    float acc[4][4];
    float4 bv = *(const float4*)&b2[j];
#pragma unroll
    for (int ri = 0; ri < 4; ri++) { acc[ri][0] = bv.x; acc[ri][1] = bv.y; acc[ri][2] = bv.z; acc[ri][3] = bv.w; }

#pragma unroll 2
    for (int k = 0; k < 128; k += 4) {
        float4 x0 = *(const float4*)&g1[rg + 0][k];
        float4 x1 = *(const float4*)&g1[rg + 1][k];
        float4 x2v = *(const float4*)&g1[rg + 2][k];
        float4 x3 = *(const float4*)&g1[rg + 3][k];
        const float* wp = w2 + (size_t)k * 256 + j;
#define PIK(comp, off) { float4 wv = *(const float4*)(wp + (off) * 256); \
    acc[0][0] += x0.comp * wv.x; acc[0][1] += x0.comp * wv.y; acc[0][2] += x0.comp * wv.z; acc[0][3] += x0.comp * wv.w; \
    acc[1][0] += x1.comp * wv.x; acc[1][1] += x1.comp * wv.y; acc[1][2] += x1.comp * wv.z; acc[1][3] += x1.comp * wv.w; \
    acc[2][0] += x2v.comp * wv.x; acc[2][1] += x2v.comp * wv.y; acc[2][2] += x2v.comp * wv.z; acc[2][3] += x2v.comp * wv.w; \
    acc[3][0] += x3.comp * wv.x; acc[3][1] += x3.comp * wv.y; acc[3][2] += x3.comp * wv.z; acc[3][3] += x3.comp * wv.w; }
        PIK(x, 0) PIK(y, 1) PIK(z, 2) PIK(w, 3)
#undef PIK
    }
#pragma unroll
    for (int ri = 0; ri < 4; ri++)
        *(float4*)&outh[(node0 + rg + ri) * HD + j] =
            make_float4(acc[ri][0], acc[ri][1], acc[ri][2], acc[ri][3]);
}

// ---------------- per-level kernel: blocks 0..255 gate, 256..511 mod ----------------
__global__ __launch_bounds__(256) void level_kernel(
    const float* __restrict__ prevh, float* __restrict__ nexth,
    const float* __restrict__ feat, const float* __restrict__ bitpos,
    const int* __restrict__ srcidx,
    const float* __restrict__ g_w1, const float* __restrict__ g_b1,
    const float* __restrict__ g_w2, const float* __restrict__ g_b2,
    const float* __restrict__ m_w1, const float* __restrict__ m_b1,
    const float* __restrict__ m_w2, const float* __restrict__ m_b2,
    const float* __restrict__ t_w1, const float* __restrict__ t_b1,
    const float* __restrict__ t_w2, const float* __restrict__ t_b2,
    const float* __restrict__ p_w1, const float* __restrict__ p_b1,
    const float* __restrict__ p_w2, const float* __restrict__ p_b2,
    const float* __restrict__ av,
    int level, int apply_relu)
{
    __shared__ float x_lds[TN][292];
    __shared__ float h1_lds[TN][132];
    __shared__ float wbuf[4096];        // 16 KB weight staging chunk
    __shared__ int   src_lds[TN * 8];
    __shared__ float bp_lds[TN * 8];
    __shared__ float dstf_lds[TN][32];
    __shared__ float ztt_lds[TN][32];
    __shared__ float smdot_lds[TN * 8];
    __shared__ float alpha_lds[TN * 8];
    __shared__ float xbp_lds[TN];
    __shared__ float av_lds[320];
    __shared__ float tw2av_lds[32];
    __shared__ float pw2av_lds[32];
    __shared__ float bias_av[2];

    const int tid = threadIdx.x;
    const bool is_gate = (blockIdx.x < 256);
    const int node0 = is_gate ? (blockIdx.x * TN) : (PGH + ((int)blockIdx.x - 256) * TN);

    const float* w1 = is_gate ? g_w1 : m_w1;
    const float* b1 = is_gate ? g_b1 : m_b1;
    const float* w2 = is_gate ? g_w2 : m_w2;
    const float* b2 = is_gate ? g_b2 : m_b2;
    const float4* wg1 = (const float4*)w1;

    // issue GEMM1 chunk-0 weight loads now; they land during the gather phase
    float4 ta = wg1[tid], tb = wg1[tid + 256], tc = wg1[tid + 512], td = wg1[tid + 768];

    if (tid < TN * 8) src_lds[tid] = srcidx[(level * NP + node0) * 8 + tid];

    if (is_gate) {
        for (int t = tid; t < TN * 32; t += 256) {
            int i = t >> 5, k = t & 31;
            x_lds[i][256 + k] = feat[((level + 1) * NP + node0 + i) * FIN + k];
        }
        __syncthreads();
        // gather + per-channel softmax over fanin, 4-node chunks (32 loads in flight)
        for (int s0 = 0; s0 < TN; s0 += 4) {
            const int* spA = &src_lds[(s0 + 0) * 8];
            const int* spB = &src_lds[(s0 + 1) * 8];
            const int* spC = &src_lds[(s0 + 2) * 8];
            const int* spD = &src_lds[(s0 + 3) * 8];
            float ma[8], mb[8], mc[8], md[8];
#pragma unroll
            for (int f = 0; f < 8; f++) ma[f] = prevh[spA[f] * HD + tid];
#pragma unroll
            for (int f = 0; f < 8; f++) mb[f] = prevh[spB[f] * HD + tid];
#pragma unroll
            for (int f = 0; f < 8; f++) mc[f] = prevh[spC[f] * HD + tid];
#pragma unroll
            for (int f = 0; f < 8; f++) md[f] = prevh[spD[f] * HD + tid];
            float mxa = -1e30f, mxb = -1e30f, mxc = -1e30f, mxd = -1e30f;
#pragma unroll
            for (int f = 0; f < 8; f++) {
                mxa = fmaxf(mxa, ma[f]); mxb = fmaxf(mxb, mb[f]);
                mxc = fmaxf(mxc, mc[f]); mxd = fmaxf(mxd, md[f]);
            }
            float sa = 0.f, wsa = 0.f, sb = 0.f, wsb = 0.f;
            float sc = 0.f, wsc = 0.f, sd = 0.f, wsd = 0.f;
#pragma unroll
            for (int f = 0; f < 8; f++) {
                float ea = __expf(ma[f] - mxa); sa += ea; wsa += ma[f] * ea;
                float eb = __expf(mb[f] - mxb); sb += eb; wsb += mb[f] * eb;
                float ec = __expf(mc[f] - mxc); sc += ec; wsc += mc[f] * ec;
                float ed = __expf(md[f] - mxd); sd += ed; wsd += md[f] * ed;
            }
            x_lds[s0 + 0][tid] = wsa / sa;
            x_lds[s0 + 1][tid] = wsb / sb;
            x_lds[s0 + 2][tid] = wsc / sc;
            x_lds[s0 + 3][tid] = wsd / sd;
        }
        __syncthreads();
    } else {
        if (tid < TN * 8) bp_lds[tid] = bitpos[(level * NP + node0) * 8 + tid];
        for (int t = tid; t < TN * 32; t += 256) {
            int i = t >> 5, k = t & 31;
            dstf_lds[i][k] = feat[((level + 1) * NP + node0 + i) * FIN + k];
        }
        for (int t = tid; t < 320; t += 256) av_lds[t] = av[t];
        __syncthreads();

        // ztt = lrelu(dstf @ t_w1 + t_b1)
        for (int t = tid; t < TN * 32; t += 256) {
            int i = t >> 5, jj = t & 31;
            float a = t_b1[jj];
#pragma unroll 8
            for (int k = 0; k < 32; k++) a += dstf_lds[i][k] * t_w1[k * 32 + jj];
            ztt_lds[i][jj] = lrelu(a);
        }
        // fold attn_vec through second MLP layers (exact linear reassociation)
        if (tid < 32) {
            float s = 0.f;
#pragma unroll 8
            for (int jj = 0; jj < 32; jj++) s += t_w2[tid * 32 + jj] * av_lds[jj];
            tw2av_lds[tid] = s;
        } else if (tid < 64) {
            int k = tid - 32;
            float s = 0.f;
#pragma unroll 8
            for (int jj = 0; jj < 32; jj++) s += p_w2[k * 32 + jj] * av_lds[32 + jj];
            pw2av_lds[k] = s;
        } else if (tid == 64) {
            float s = 0.f;
#pragma unroll 8
            for (int jj = 0; jj < 32; jj++) s += t_b2[jj] * av_lds[jj];
            bias_av[0] = s;
        } else if (tid == 65) {
            float s = 0.f;
#pragma unroll 8
            for (int jj = 0; jj < 32; jj++) s += p_b2[jj] * av_lds[32 + jj];
            bias_av[1] = s;
        }
        // sm . av[64:320] per gathered row: 4 waves x 32 rows, 8-row chunks
        {
            const int wave = tid >> 6, lane = tid & 63;
            float4 av4 = *(const float4*)&av_lds[64 + lane * 4];
            for (int t0 = 0; t0 < 32; t0 += 8) {
                float4 x0 = *(const float4*)&prevh[src_lds[wave + 4 * (t0 + 0)] * HD + lane * 4];
                float4 x1 = *(const float4*)&prevh[src_lds[wave + 4 * (t0 + 1)] * HD + lane * 4];
                float4 x2v = *(const float4*)&prevh[src_lds[wave + 4 * (t0 + 2)] * HD + lane * 4];
                float4 x3 = *(const float4*)&prevh[src_lds[wave + 4 * (t0 + 3)] * HD + lane * 4];
                float4 x4 = *(const float4*)&prevh[src_lds[wave + 4 * (t0 + 4)] * HD + lane * 4];
                float4 x5 = *(const float4*)&prevh[src_lds[wave + 4 * (t0 + 5)] * HD + lane * 4];
                float4 x6 = *(const float4*)&prevh[src_lds[wave + 4 * (t0 + 6)] * HD + lane * 4];
                float4 x7 = *(const float4*)&prevh[src_lds[wave + 4 * (t0 + 7)] * HD + lane * 4];
                float p0 = x0.x * av4.x + x0.y * av4.y + x0.z * av4.z + x0.w * av4.w;
                float p1 = x1.x * av4.x + x1.y * av4.y + x1.z * av4.z + x1.w * av4.w;
                float p2 = x2v.x * av4.x + x2v.y * av4.y + x2v.z * av4.z + x2v.w * av4.w;
                float p3 = x3.x * av4.x + x3.y * av4.y + x3.z * av4.z + x3.w * av4.w;
                float p4 = x4.x * av4.x + x4.y * av4.y + x4.z * av4.z + x4.w * av4.w;
                float p5 = x5.x * av4.x + x5.y * av4.y + x5.z * av4.z + x5.w * av4.w;
                float p6 = x6.x * av4.x + x6.y * av4.y + x6.z * av4.z + x6.w * av4.w;
                float p7 = x7.x * av4.x + x7.y * av4.y + x7.z * av4.z + x7.w * av4.w;
#pragma unroll
                for (int off = 32; off > 0; off >>= 1) {
                    p0 += __shfl_xor(p0, off); p1 += __shfl_xor(p1, off);
                    p2 += __shfl_xor(p2, off); p3 += __shfl_xor(p3, off);
                    p4 += __shfl_xor(p4, off); p5 += __shfl_xor(p5, off);
                    p6 += __shfl_xor(p6, off); p7 += __shfl_xor(p7, off);
                }
                if (lane == 0) {
                    smdot_lds[wave + 4 * (t0 + 0)] = p0;
                    smdot_lds[wave + 4 * (t0 + 1)] = p1;
                    smdot_lds[wave + 4 * (t0 + 2)] = p2;
                    smdot_lds[wave + 4 * (t0 + 3)] = p3;
                    smdot_lds[wave + 4 * (t0 + 4)] = p4;
                    smdot_lds[wave + 4 * (t0 + 5)] = p5;
                    smdot_lds[wave + 4 * (t0 + 6)] = p6;
                    smdot_lds[wave + 4 * (t0 + 7)] = p7;
                }
            }
        }
        __syncthreads();

        // logits + softmax over fanin: tid = i*16 + f*2 + jg
        {
            const int jg = tid & 1, f = (tid >> 1) & 7, i = tid >> 4;
            const float bpv = bp_lds[i * 8 + f];
            float part = 0.f;
            const int k0 = jg * 16;
#pragma unroll
            for (int k = k0; k < k0 + 16; k++) {
                float h1pk = lrelu(bpv * p_w1[k] + p_b1[k]);
                part += h1pk * pw2av_lds[k];
                part += ztt_lds[i][k] * tw2av_lds[k];
            }
            part += __shfl_xor(part, 1);
            float logit = part + bias_av[0] + bias_av[1] + smdot_lds[i * 8 + f];
            float mx = logit;
            mx = fmaxf(mx, __shfl_xor(mx, 2));
            mx = fmaxf(mx, __shfl_xor(mx, 4));
            mx = fmaxf(mx, __shfl_xor(mx, 8));
            float e = __expf(logit - mx);
            float ssum = e;
            ssum += __shfl_xor(ssum, 2);
            ssum += __shfl_xor(ssum, 4);
            ssum += __shfl_xor(ssum, 8);
            float alpha = e / ssum;
            if (jg == 0) alpha_lds[i * 8 + f] = alpha;
            float ab = alpha * bpv;
            ab += __shfl_xor(ab, 2);
            ab += __shfl_xor(ab, 4);
            ab += __shfl_xor(ab, 8);
            if ((tid & 15) == 0) xbp_lds[i] = ab;
        }
        __syncthreads();

        // neigh_m, 4-node chunks (32 loads in flight) + assemble x
        for (int s0 = 0; s0 < TN; s0 += 4) {
            const int* spA = &src_lds[(s0 + 0) * 8];
            const int* spB = &src_lds[(s0 + 1) * 8];
            const int* spC = &src_lds[(s0 + 2) * 8];
            const int* spD = &src_lds[(s0 + 3) * 8];
            float ma[8], mb[8], mc[8], md[8];
#pragma unroll
            for (int f = 0; f < 8; f++) ma[f] = prevh[spA[f] * HD + tid];
#pragma unroll
            for (int f = 0; f < 8; f++) mb[f] = prevh[spB[f] * HD + tid];
#pragma unroll
            for (int f = 0; f < 8; f++) mc[f] = prevh[spC[f] * HD + tid];
#pragma unroll
            for (int f = 0; f < 8; f++) md[f] = prevh[spD[f] * HD + tid];
            const float* apA = &alpha_lds[(s0 + 0) * 8];
            const float* apB = &alpha_lds[(s0 + 1) * 8];
            const float* apC = &alpha_lds[(s0 + 2) * 8];
            const float* apD = &alpha_lds[(s0 + 3) * 8];
            float aa = 0.f, ab2 = 0.f, ac = 0.f, ad = 0.f;
#pragma unroll
            for (int f = 0; f < 8; f++) {
                aa  += apA[f] * ma[f]; ab2 += apB[f] * mb[f];
                ac  += apC[f] * mc[f]; ad  += apD[f] * md[f];
            }
            x_lds[s0 + 0][tid] = aa;
            x_lds[s0 + 1][tid] = ab2;
            x_lds[s0 + 2][tid] = ac;
            x_lds[s0 + 3][tid] = ad;
        }
        if (tid < TN) x_lds[tid][256] = xbp_lds[tid];
        for (int t = tid; t < TN * 32; t += 256) {
            int i = t >> 5, k = t & 31;
            x_lds[i][257 + k] = dstf_lds[i][k];
        }
        __syncthreads();
    }

    // ---------- GEMM1: (TN x K1) @ (K1 x 128) + b1, leaky; async LDS-staged weights ----------
    {
        const int j = (tid & 63) * 2;
        const int rg = (tid >> 6) * 4;
        float acc[4][2];
        float2 bv = *(const float2*)&b1[j];
#pragma unroll
        for (int ri = 0; ri < 4; ri++) { acc[ri][0] = bv.x; acc[ri][1] = bv.y; }

        float4* w4 = (float4*)wbuf;
        for (int c = 0; c < 9; ++c) {            // 9 chunks of 32 k (32x128 = 1024 float4)
            __syncthreads();                     // wbuf free
            w4[tid] = ta; w4[tid + 256] = tb; w4[tid + 512] = tc; w4[tid + 768] = td;
            if (c < 8) {                         // issue next chunk; lands during compute
                const float4* gn = wg1 + (size_t)(c + 1) * 1024;
                ta = gn[tid]; tb = gn[tid + 256]; tc = gn[tid + 512]; td = gn[tid + 768];
            }
            __syncthreads();                     // wbuf ready
            const int kc = c * 32;
#pragma unroll 2
            for (int k = 0; k < 32; k += 4) {
                float4 x0 = *(const float4*)&x_lds[rg + 0][kc + k];
                float4 x1 = *(const float4*)&x_lds[rg + 1][kc + k];
                float4 x2v = *(const float4*)&x_lds[rg + 2][kc + k];
                float4 x3 = *(const float4*)&x_lds[rg + 3][kc + k];
                const float* wp = wbuf + k * 128 + j;
#define G1K(comp, off) { float2 wv = *(const float2*)(wp + (off) * 128); \
    acc[0][0] += x0.comp * wv.x; acc[0][1] += x0.comp * wv.y; \
    acc[1][0] += x1.comp * wv.x; acc[1][1] += x1.comp * wv.y; \
    acc[2][0] += x2v.comp * wv.x; acc[2][1] += x2v.comp * wv.y; \
    acc[3][0] += x3.comp * wv.x; acc[3][1] += x3.comp * wv.y; }
                G1K(x, 0) G1K(y, 1) G1K(z, 2) G1K(w, 3)
#undef G1K
            }
        }
        if (!is_gate) {
            float2 wt = *(const float2*)&w1[288 * 128 + j];
#pragma unroll
            for (int ri = 0; ri < 4; ri++) {
                float xb = x_lds[rg + ri][288];
                acc[ri][0] += xb * wt.x; acc[ri][1] += xb * wt.y;
            }
        }
#pragma unroll
        for (int ri = 0; ri < 4; ri++)
            *(float2*)&h1_lds[rg + ri][j] = make_float2(lrelu(acc[ri][0]), lrelu(acc[ri][1]));
    }
    __syncthreads();

    // ---------- GEMM2: (TN x 128) @ (128 x 256) + b2 (+relu); async LDS-staged ----------
    {
        const int j = (tid & 63) * 4;
        const int rg = (tid >> 6) * 4;
        float acc[4][4];
        float4 bv = *(const float4*)&b2[j];
#pragma unroll
        for (int ri = 0; ri < 4; ri++) { acc[ri][0] = bv.x; acc[ri][1] = bv.y; acc[ri][2] = bv.z; acc[ri][3] = bv.w; }

        const float4* wg2 = (const float4*)w2;
        float4* w4 = (float4*)wbuf;
        ta = wg2[tid]; tb = wg2[tid + 256]; tc = wg2[tid + 512]; td = wg2[tid + 768];
        for (int c = 0; c < 8; ++c) {            // 8 chunks of 16 k (16x256 = 1024 float4)
            __syncthreads();
            w4[tid] = ta; w4[tid + 256] = tb; w4[tid + 512] = tc; w4[tid + 768] = td;
            if (c < 7) {
                const float4* gn = wg2 + (size_t)(c + 1) * 1024;
                ta = gn[tid]; tb = gn[tid + 256]; tc = gn[tid + 512]; td = gn[tid + 768];
            }
            __syncthreads();
            const int kc = c * 16;
#pragma unroll 2
            for (int k = 0; k < 16; k += 4) {
                float4 x0 = *(const float4*)&h1_lds[rg + 0][kc + k];
                float4 x1 = *(const float4*)&h1_lds[rg + 1][kc + k];
                float4 x2v = *(const float4*)&h1_lds[rg + 2][kc + k];
                float4 x3 = *(const float4*)&h1_lds[rg + 3][kc + k];
                const float* wp = wbuf + k * 256 + j;
#define G2K(comp, off) { float4 wv = *(const float4*)(wp + (off) * 256); \
    acc[0][0] += x0.comp * wv.x; acc[0][1] += x0.comp * wv.y; acc[0][2] += x0.comp * wv.z; acc[0][3] += x0.comp * wv.w; \
    acc[1][0] += x1.comp * wv.x; acc[1][1] += x1.comp * wv.y; acc[1][2] += x1.comp * wv.z; acc[1][3] += x1.comp * wv.w; \
    acc[2][0] += x2v.comp * wv.x; acc[2][1] += x2v.comp * wv.y; acc[2][2] += x2v.comp * wv.z; acc[2][3] += x2v.comp * wv.w; \
    acc[3][0] += x3.comp * wv.x; acc[3][1] += x3.comp * wv.y; acc[3][2] += x3.comp * wv.z; acc[3][3] += x3.comp * wv.w; }
                G2K(x, 0) G2K(y, 1) G2K(z, 2) G2K(w, 3)
#undef G2K
            }
        }
#pragma unroll
        for (int ri = 0; ri < 4; ri++) {
            if (apply_relu) {
#pragma unroll
                for (int ci = 0; ci < 4; ci++) acc[ri][ci] = fmaxf(acc[ri][ci], 0.f);
            }
            *(float4*)&nexth[(node0 + rg + ri) * HD + j] =
                make_float4(acc[ri][0], acc[ri][1], acc[ri][2], acc[ri][3]);
        }
    }
}

// ---------------- final kernel: glob mlp + concat + out mlp (fused) ----------------
__global__ __launch_bounds__(256) void final_kernel(
    const float* __restrict__ prevh, const float* __restrict__ pofeat,
    const float* __restrict__ gl_w1, const float* __restrict__ gl_b1,
    const float* __restrict__ gl_w2, const float* __restrict__ gl_b2,
    const float* __restrict__ o_w1, const float* __restrict__ o_b1,
    const float* __restrict__ o_w2, const float* __restrict__ o_b2,
    float* __restrict__ out)
{
    __shared__ float x2[TN][516];
    __shared__ float g1[TN][132];
    __shared__ float wbuf[4096];
    __shared__ float ow2_lds[256];

    const int tid = threadIdx.x;
    const int node0 = blockIdx.x * TN;
    const int j = (tid & 63) * 4;
    const int rg = (tid >> 6) * 4;

    const float4* wgl = (const float4*)gl_w2;
    float4 ta = wgl[tid], tb = wgl[tid + 256], tc = wgl[tid + 512], td = wgl[tid + 768];

    for (int q = tid; q < TN * 64; q += 256) {
        int i = q >> 6, c4 = (q & 63) * 4;
        *(float4*)&x2[i][c4] = *(const float4*)&prevh[(node0 + i) * HD + c4];
    }
    for (int t = tid; t < TN * 128; t += 256) {
        int i = t >> 7, jj = t & 127;
        g1[i][jj] = lrelu(pofeat[node0 + i] * gl_w1[jj] + gl_b1[jj]);
    }
    ow2_lds[tid] = o_w2[tid];

    // glob layer 2: (TN x 128)@(128 x 256) -> x2 cols 256..511, async staged
    {
        float acc[4][4];
        float4 bv = *(const float4*)&gl_b2[j];
#pragma unroll
        for (int ri = 0; ri < 4; ri++) { acc[ri][0] = bv.x; acc[ri][1] = bv.y; acc[ri][2] = bv.z; acc[ri][3] = bv.w; }
        float4* w4 = (float4*)wbuf;
        for (int c = 0; c < 8; ++c) {
            __syncthreads();
            w4[tid] = ta; w4[tid + 256] = tb; w4[tid + 512] = tc; w4[tid + 768] = td;
            if (c < 7) {
                const float4* gn = wgl + (size_t)(c + 1) * 1024;
                ta = gn[tid]; tb = gn[tid + 256]; tc = gn[tid + 512]; td = gn[tid + 768];
            } else {
                const float4* gn = (const float4*)o_w1;   // prefetch out1 chunk 0
                ta = gn[tid]; tb = gn[tid + 256]; tc = gn[tid + 512]; td = gn[tid + 768];
            }
            __syncthreads();
            const int kc = c * 16;
#pragma unroll 2
            for (int k = 0; k < 16; k += 4) {
                float4 x0 = *(const float4*)&g1[rg + 0][kc + k];
                float4 x1 = *(const float4*)&g1[rg + 1][kc + k];
                float4 x2v = *(const float4*)&g1[rg + 2][kc + k];
                float4 x3 = *(const float4*)&g1[rg + 3][kc + k];
                const float* wp = wbuf + k * 256 + j;
#define GLK(comp, off) { float4 wv = *(const float4*)(wp + (off) * 256); \
    acc[0][0] += x0.comp * wv.x; acc[0][1] += x0.comp * wv.y; acc[0][2] += x0.comp * wv.z; acc[0][3] += x0.comp * wv.w; \
    acc[1][0] += x1.comp * wv.x; acc[1][1] += x1.comp * wv.y; acc[1][2] += x1.comp * wv.z; acc[1][3] += x1.comp * wv.w; \
    acc[2][0] += x2v.comp * wv.x; acc[2][1] += x2v.comp * wv.y; acc[2][2] += x2v.comp * wv.z; acc[2][3] += x2v.comp * wv.w; \
    acc[3][0] += x3.comp * wv.x; acc[3][1] += x3.comp * wv.y; acc[3][2] += x3.comp * wv.z; acc[3][3] += x3.comp * wv.w; }
                GLK(x, 0) GLK(y, 1) GLK(z, 2) GLK(w, 3)
#undef GLK
            }
        }
        __syncthreads();
#pragma unroll
        for (int ri = 0; ri < 4; ri++)
            *(float4*)&x2[rg + ri][256 + j] = make_float4(acc[ri][0], acc[ri][1], acc[ri][2], acc[ri][3]);
        __syncthreads();
    }

    // out layer 1 (async staged, 32 chunks) fused with out layer 2 (wave reduction)
    {
        float acc[4][4];
        float4 bv = *(const float4*)&o_b1[j];
#pragma unroll
        for (int ri = 0; ri < 4; ri++) { acc[ri][0] = bv.x; acc[ri][1] = bv.y; acc[ri][2] = bv.z; acc[ri][3] = bv.w; }
        const float4* wo = (const float4*)o_w1;
        float4* w4 = (float4*)wbuf;
        for (int c = 0; c < 32; ++c) {
            __syncthreads();
            w4[tid] = ta; w4[tid + 256] = tb; w4[tid + 512] = tc; w4[tid + 768] = td;
            if (c < 31) {
                const float4* gn = wo + (size_t)(c + 1) * 1024;
                ta = gn[tid]; tb = gn[tid + 256]; tc = gn[tid + 512]; td = gn[tid + 768];
            }
            __syncthreads();
            const int kc = c * 16;
#pragma unroll 2
            for (int k = 0; k < 16; k += 4) {
                float4 x0 = *(const float4*)&x2[rg + 0][kc + k];
                float4 x1 = *(const float4*)&x2[rg + 1][kc + k];
                float4 x2v = *(const float4*)&x2[rg + 2][kc + k];
                float4 x3 = *(const float4*)&x2[rg + 3][kc + k];
                const float* wp = wbuf + k * 256 + j;
#define O1K(comp, off) { float4 wv = *(const float4*)(wp + (off) * 256); \
    acc[0][0] += x0.comp * wv.x; acc[0][1] += x0.comp * wv.y; acc[0][2] += x0.comp * wv.z; acc[0][3] += x0.comp * wv.w; \
    acc[1][0] += x1.comp * wv.x; acc[1][1] += x1.comp * wv.y; acc[1][2] += x1.comp * wv.z; acc[1][3] += x1.comp * wv.w; \
    acc[2][0] += x2v.comp * wv.x; acc[2][1] += x2v.comp * wv.y; acc[2][2] += x2v.comp * wv.z; acc[2][3] += x2v.comp * wv.w; \
    acc[3][0] += x3.comp * wv.x; acc[3][1] += x3.comp * wv.y; acc[3][2] += x3.comp * wv.z; acc[3][3] += x3.comp * wv.w; }
                O1K(x, 0) O1K(y, 1) O1K(z, 2) O1K(w, 3)
#undef O1K
            }
        }
        // out layer 2: each wave's 64 lanes cover cols 0..255 for rows rg..rg+3
        float4 wv = *(const float4*)&ow2_lds[j];
        float ob = o_b2[0];
#pragma unroll
        for (int ri = 0; ri < 4; ri++) {
            float p = lrelu(acc[ri][0]) * wv.x + lrelu(acc[ri][1]) * wv.y
                    + lrelu(acc[ri][2]) * wv.z + lrelu(acc[ri][3]) * wv.w;
#pragma unroll
            for (int off = 1; off < 64; off <<= 1) p += __shfl_xor(p, off);
            if ((tid & 63) == 0) out[node0 + rg + ri] = p + ob;
        }
    }
}

extern "C" void kernel_launch(void* const* d_in, const int* in_sizes, int n_in,
                              void* d_out, int out_size, void* d_ws, size_t ws_size,
                              hipStream_t stream)
{
    const float* delay    = (const float*)d_in[0];
    const float* feat     = (const float*)d_in[1];
    const float* bitpos   = (const float*)d_in[2];
    const float* pofeat   = (const float*)d_in[3];
    const int*   srcidx   = (const int*)  d_in[4];
    const float* pi_w1    = (const float*)d_in[5];
    const float* pi_b1    = (const float*)d_in[6];
    const float* pi_w2    = (const float*)d_in[7];
    const float* pi_b2    = (const float*)d_in[8];
    const float* gate_w1  = (const float*)d_in[9];
    const float* gate_b1  = (const float*)d_in[10];
    const float* gate_w2  = (const float*)d_in[11];
    const float* gate_b2  = (const float*)d_in[12];
    const float* mod_w1   = (const float*)d_in[13];
    const float* mod_b1   = (const float*)d_in[14];
    const float* mod_w2   = (const float*)d_in[15];
    const float* mod_b2   = (const float*)d_in[16];
    const float* type_w1  = (const float*)d_in[17];
    const float* type_b1  = (const float*)d_in[18];
    const float* type_w2  = (const float*)d_in[19];
    const float* type_b2  = (const float*)d_in[20];
    const float* pos_w1   = (const float*)d_in[21];
    const float* pos_b1   = (const float*)d_in[22];
    const float* pos_w2   = (const float*)d_in[23];
    const float* pos_b2   = (const float*)d_in[24];
    const float* attn_vec = (const float*)d_in[25];
    const float* glob_w1  = (const float*)d_in[26];
    const float* glob_b1  = (const float*)d_in[27];
    const float* glob_w2  = (const float*)d_in[28];
    const float* glob_b2  = (const float*)d_in[29];
    const float* out_w1   = (const float*)d_in[30];
    const float* out_b1   = (const float*)d_in[31];
    const float* out_w2   = (const float*)d_in[32];
    const float* out_b2   = (const float*)d_in[33];

    float* buf0 = (float*)d_ws;
    float* buf1 = buf0 + (size_t)NP * HD;

    pi_kernel<<<NP / TN, 256, 0, stream>>>(delay, pi_w1, pi_b1, pi_w2, pi_b2, buf0);

    for (int l = 0; l < NLVL; l++) {
        float* pv = (l & 1) ? buf1 : buf0;
        float* nx = (l & 1) ? buf0 : buf1;
        level_kernel<<<NP / TN, 256, 0, stream>>>(
            pv, nx, feat, bitpos, srcidx,
            gate_w1, gate_b1, gate_w2, gate_b2,
            mod_w1, mod_b1, mod_w2, mod_b2,
            type_w1, type_b1, type_w2, type_b2,
            pos_w1, pos_b1, pos_w2, pos_b2,
            attn_vec, l, (l != NLVL - 1) ? 1 : 0);
    }

    final_kernel<<<NP / TN, 256, 0, stream>>>(
        buf1, pofeat,
        glob_w1, glob_b1, glob_w2, glob_b2,
        out_w1, out_b1, out_w2, out_b2,
        (float*)d_out);
}

// Round 9
// 605.512 us; speedup vs baseline: 10.0264x; 1.1087x over previous
//
#include <hip/hip_runtime.h>
#include <math.h>

#define HD   256
#define FIN  32
#define NP   8192
#define PGH  4096
#define NLVL 15
#define TN   16    // nodes per block tile

__device__ __forceinline__ float lrelu(float x) { return x > 0.f ? x : 0.1f * x; }

// ---------------- pi kernel: prev_h = mlp(delay), + sdot epilogue ----------------
__global__ __launch_bounds__(256) void pi_kernel(
    const float* __restrict__ delay,
    const float* __restrict__ w1, const float* __restrict__ b1,
    const float* __restrict__ w2, const float* __restrict__ b2,
    const float* __restrict__ av,
    float* __restrict__ outh, float* __restrict__ sdot)
{
    __shared__ float g1[TN][132];
    const int tid = threadIdx.x;
    const int node0 = blockIdx.x * TN;

    for (int t = tid; t < TN * 128; t += 256) {
        int i = t >> 7, jj = t & 127;
        g1[i][jj] = lrelu(delay[node0 + i] * w1[jj] + b1[jj]);
    }
    __syncthreads();

    const int j = (tid & 63) * 4;
    const int rg = (tid >> 6) * 4;
    float acc[4][4];
    float4 bv = *(const float4*)&b2[j];
#pragma unroll
    for (int ri = 0; ri < 4; ri++) { acc[ri][0] = bv.x; acc[ri][1] = bv.y; acc[ri][2] = bv.z; acc[ri][3] = bv.w; }

#pragma unroll 2
    for (int k = 0; k < 128; k += 4) {
        float4 x0 = *(const float4*)&g1[rg + 0][k];
        float4 x1 = *(const float4*)&g1[rg + 1][k];
        float4 x2v = *(const float4*)&g1[rg + 2][k];
        float4 x3 = *(const float4*)&g1[rg + 3][k];
        const float* wp = w2 + (size_t)k * 256 + j;
#define PIK(comp, off) { float4 wv = *(const float4*)(wp + (off) * 256); \
    acc[0][0] += x0.comp * wv.x; acc[0][1] += x0.comp * wv.y; acc[0][2] += x0.comp * wv.z; acc[0][3] += x0.comp * wv.w; \
    acc[1][0] += x1.comp * wv.x; acc[1][1] += x1.comp * wv.y; acc[1][2] += x1.comp * wv.z; acc[1][3] += x1.comp * wv.w; \
    acc[2][0] += x2v.comp * wv.x; acc[2][1] += x2v.comp * wv.y; acc[2][2] += x2v.comp * wv.z; acc[2][3] += x2v.comp * wv.w; \
    acc[3][0] += x3.comp * wv.x; acc[3][1] += x3.comp * wv.y; acc[3][2] += x3.comp * wv.z; acc[3][3] += x3.comp * wv.w; }
        PIK(x, 0) PIK(y, 1) PIK(z, 2) PIK(w, 3)
#undef PIK
    }
    float4 avj = *(const float4*)&av[64 + j];
#pragma unroll
    for (int ri = 0; ri < 4; ri++) {
        *(float4*)&outh[(node0 + rg + ri) * HD + j] =
            make_float4(acc[ri][0], acc[ri][1], acc[ri][2], acc[ri][3]);
        float p = acc[ri][0] * avj.x + acc[ri][1] * avj.y + acc[ri][2] * avj.z + acc[ri][3] * avj.w;
#pragma unroll
        for (int off = 1; off < 64; off <<= 1) p += __shfl_xor(p, off);
        if ((tid & 63) == 0) sdot[node0 + rg + ri] = p;
    }
}

// ---------------- per-level kernel: blocks 0..255 gate, 256..511 mod ----------------
__global__ __launch_bounds__(256) void level_kernel(
    const float* __restrict__ prevh, float* __restrict__ nexth,
    const float* __restrict__ sdot_prev, float* __restrict__ sdot_next,
    const float* __restrict__ feat, const float* __restrict__ bitpos,
    const int* __restrict__ srcidx,
    const float* __restrict__ g_w1, const float* __restrict__ g_b1,
    const float* __restrict__ g_w2, const float* __restrict__ g_b2,
    const float* __restrict__ m_w1, const float* __restrict__ m_b1,
    const float* __restrict__ m_w2, const float* __restrict__ m_b2,
    const float* __restrict__ t_w1, const float* __restrict__ t_b1,
    const float* __restrict__ t_w2, const float* __restrict__ t_b2,
    const float* __restrict__ p_w1, const float* __restrict__ p_b1,
    const float* __restrict__ p_w2, const float* __restrict__ p_b2,
    const float* __restrict__ av,
    int level, int apply_relu)
{
    __shared__ float x_lds[TN][292];
    __shared__ float h1_lds[TN][132];
    __shared__ float wbuf[4096];        // 16 KB weight staging chunk
    __shared__ int   src_lds[TN * 8];
    __shared__ float bp_lds[TN * 8];
    __shared__ float dstf_lds[TN][32];
    __shared__ float ztt_lds[TN][32];
    __shared__ float alpha_lds[TN * 8];
    __shared__ float xbp_lds[TN];
    __shared__ float av_lds[64];
    __shared__ float tw2av_lds[32];
    __shared__ float pw2av_lds[32];
    __shared__ float bias_av[2];

    const int tid = threadIdx.x;
    const bool is_gate = (blockIdx.x < 256);
    const int node0 = is_gate ? (blockIdx.x * TN) : (PGH + ((int)blockIdx.x - 256) * TN);

    const float* w1 = is_gate ? g_w1 : m_w1;
    const float* b1 = is_gate ? g_b1 : m_b1;
    const float* w2 = is_gate ? g_w2 : m_w2;
    const float* b2 = is_gate ? g_b2 : m_b2;
    const float4* wg1 = (const float4*)w1;

    // issue GEMM1 chunk-0 weight loads now; they land during the gather phase
    float4 ta = wg1[tid], tb = wg1[tid + 256], tc = wg1[tid + 512], td = wg1[tid + 768];

    if (tid < TN * 8) src_lds[tid] = srcidx[(level * NP + node0) * 8 + tid];

    if (is_gate) {
        for (int t = tid; t < TN * 32; t += 256) {
            int i = t >> 5, k = t & 31;
            x_lds[i][256 + k] = feat[((level + 1) * NP + node0 + i) * FIN + k];
        }
        __syncthreads();
        // gather + per-channel softmax over fanin, 4-node chunks (32 loads in flight)
        for (int s0 = 0; s0 < TN; s0 += 4) {
            const int* spA = &src_lds[(s0 + 0) * 8];
            const int* spB = &src_lds[(s0 + 1) * 8];
            const int* spC = &src_lds[(s0 + 2) * 8];
            const int* spD = &src_lds[(s0 + 3) * 8];
            float ma[8], mb[8], mc[8], md[8];
#pragma unroll
            for (int f = 0; f < 8; f++) ma[f] = prevh[spA[f] * HD + tid];
#pragma unroll
            for (int f = 0; f < 8; f++) mb[f] = prevh[spB[f] * HD + tid];
#pragma unroll
            for (int f = 0; f < 8; f++) mc[f] = prevh[spC[f] * HD + tid];
#pragma unroll
            for (int f = 0; f < 8; f++) md[f] = prevh[spD[f] * HD + tid];
            float mxa = -1e30f, mxb = -1e30f, mxc = -1e30f, mxd = -1e30f;
#pragma unroll
            for (int f = 0; f < 8; f++) {
                mxa = fmaxf(mxa, ma[f]); mxb = fmaxf(mxb, mb[f]);
                mxc = fmaxf(mxc, mc[f]); mxd = fmaxf(mxd, md[f]);
            }
            float sa = 0.f, wsa = 0.f, sb = 0.f, wsb = 0.f;
            float sc = 0.f, wsc = 0.f, sd = 0.f, wsd = 0.f;
#pragma unroll
            for (int f = 0; f < 8; f++) {
                float ea = __expf(ma[f] - mxa); sa += ea; wsa += ma[f] * ea;
                float eb = __expf(mb[f] - mxb); sb += eb; wsb += mb[f] * eb;
                float ec = __expf(mc[f] - mxc); sc += ec; wsc += mc[f] * ec;
                float ed = __expf(md[f] - mxd); sd += ed; wsd += md[f] * ed;
            }
            x_lds[s0 + 0][tid] = wsa / sa;
            x_lds[s0 + 1][tid] = wsb / sb;
            x_lds[s0 + 2][tid] = wsc / sc;
            x_lds[s0 + 3][tid] = wsd / sd;
        }
        __syncthreads();
    } else {
        if (tid < TN * 8) bp_lds[tid] = bitpos[(level * NP + node0) * 8 + tid];
        for (int t = tid; t < TN * 32; t += 256) {
            int i = t >> 5, k = t & 31;
            dstf_lds[i][k] = feat[((level + 1) * NP + node0 + i) * FIN + k];
        }
        if (tid < 64) av_lds[tid] = av[tid];
        __syncthreads();

        // ztt = lrelu(dstf @ t_w1 + t_b1)
        for (int t = tid; t < TN * 32; t += 256) {
            int i = t >> 5, jj = t & 31;
            float a = t_b1[jj];
#pragma unroll 8
            for (int k = 0; k < 32; k++) a += dstf_lds[i][k] * t_w1[k * 32 + jj];
            ztt_lds[i][jj] = lrelu(a);
        }
        // fold attn_vec through second MLP layers (exact linear reassociation)
        if (tid < 32) {
            float s = 0.f;
#pragma unroll 8
            for (int jj = 0; jj < 32; jj++) s += t_w2[tid * 32 + jj] * av_lds[jj];
            tw2av_lds[tid] = s;
        } else if (tid < 64) {
            int k = tid - 32;
            float s = 0.f;
#pragma unroll 8
            for (int jj = 0; jj < 32; jj++) s += p_w2[k * 32 + jj] * av_lds[32 + jj];
            pw2av_lds[k] = s;
        } else if (tid == 64) {
            float s = 0.f;
#pragma unroll 8
            for (int jj = 0; jj < 32; jj++) s += t_b2[jj] * av_lds[jj];
            bias_av[0] = s;
        } else if (tid == 65) {
            float s = 0.f;
#pragma unroll 8
            for (int jj = 0; jj < 32; jj++) s += p_b2[jj] * av_lds[32 + jj];
            bias_av[1] = s;
        }
        __syncthreads();

        // logits + softmax over fanin: tid = i*16 + f*2 + jg  (sm.av via hoisted sdot)
        {
            const int jg = tid & 1, f = (tid >> 1) & 7, i = tid >> 4;
            const float sv = sdot_prev[src_lds[i * 8 + f]];   // hoisted row dot
            const float bpv = bp_lds[i * 8 + f];
            float part = 0.f;
            const int k0 = jg * 16;
#pragma unroll
            for (int k = k0; k < k0 + 16; k++) {
                float h1pk = lrelu(bpv * p_w1[k] + p_b1[k]);
                part += h1pk * pw2av_lds[k];
                part += ztt_lds[i][k] * tw2av_lds[k];
            }
            part += __shfl_xor(part, 1);
            float logit = part + bias_av[0] + bias_av[1] + sv;
            float mx = logit;
            mx = fmaxf(mx, __shfl_xor(mx, 2));
            mx = fmaxf(mx, __shfl_xor(mx, 4));
            mx = fmaxf(mx, __shfl_xor(mx, 8));
            float e = __expf(logit - mx);
            float ssum = e;
            ssum += __shfl_xor(ssum, 2);
            ssum += __shfl_xor(ssum, 4);
            ssum += __shfl_xor(ssum, 8);
            float alpha = e / ssum;
            if (jg == 0) alpha_lds[i * 8 + f] = alpha;
            float ab = alpha * bpv;
            ab += __shfl_xor(ab, 2);
            ab += __shfl_xor(ab, 4);
            ab += __shfl_xor(ab, 8);
            if ((tid & 15) == 0) xbp_lds[i] = ab;
        }
        __syncthreads();

        // neigh_m, 4-node chunks (32 loads in flight) + assemble x
        for (int s0 = 0; s0 < TN; s0 += 4) {
            const int* spA = &src_lds[(s0 + 0) * 8];
            const int* spB = &src_lds[(s0 + 1) * 8];
            const int* spC = &src_lds[(s0 + 2) * 8];
            const int* spD = &src_lds[(s0 + 3) * 8];
            float ma[8], mb[8], mc[8], md[8];
#pragma unroll
            for (int f = 0; f < 8; f++) ma[f] = prevh[spA[f] * HD + tid];
#pragma unroll
            for (int f = 0; f < 8; f++) mb[f] = prevh[spB[f] * HD + tid];
#pragma unroll
            for (int f = 0; f < 8; f++) mc[f] = prevh[spC[f] * HD + tid];
#pragma unroll
            for (int f = 0; f < 8; f++) md[f] = prevh[spD[f] * HD + tid];
            const float* apA = &alpha_lds[(s0 + 0) * 8];
            const float* apB = &alpha_lds[(s0 + 1) * 8];
            const float* apC = &alpha_lds[(s0 + 2) * 8];
            const float* apD = &alpha_lds[(s0 + 3) * 8];
            float aa = 0.f, ab2 = 0.f, ac = 0.f, ad = 0.f;
#pragma unroll
            for (int f = 0; f < 8; f++) {
                aa  += apA[f] * ma[f]; ab2 += apB[f] * mb[f];
                ac  += apC[f] * mc[f]; ad  += apD[f] * md[f];
            }
            x_lds[s0 + 0][tid] = aa;
            x_lds[s0 + 1][tid] = ab2;
            x_lds[s0 + 2][tid] = ac;
            x_lds[s0 + 3][tid] = ad;
        }
        if (tid < TN) x_lds[tid][256] = xbp_lds[tid];
        for (int t = tid; t < TN * 32; t += 256) {
            int i = t >> 5, k = t & 31;
            x_lds[i][257 + k] = dstf_lds[i][k];
        }
        __syncthreads();
    }

    // ---------- GEMM1: (TN x K1) @ (K1 x 128) + b1, leaky; async LDS-staged weights ----------
    {
        const int j = (tid & 63) * 2;
        const int rg = (tid >> 6) * 4;
        float acc[4][2];
        float2 bv = *(const float2*)&b1[j];
#pragma unroll
        for (int ri = 0; ri < 4; ri++) { acc[ri][0] = bv.x; acc[ri][1] = bv.y; }

        float4* w4 = (float4*)wbuf;
        for (int c = 0; c < 9; ++c) {            // 9 chunks of 32 k (32x128 = 1024 float4)
            __syncthreads();                     // wbuf free
            w4[tid] = ta; w4[tid + 256] = tb; w4[tid + 512] = tc; w4[tid + 768] = td;
            if (c < 8) {                         // issue next chunk; lands during compute
                const float4* gn = wg1 + (size_t)(c + 1) * 1024;
                ta = gn[tid]; tb = gn[tid + 256]; tc = gn[tid + 512]; td = gn[tid + 768];
            }
            __syncthreads();                     // wbuf ready
            const int kc = c * 32;
#pragma unroll 2
            for (int k = 0; k < 32; k += 4) {
                float4 x0 = *(const float4*)&x_lds[rg + 0][kc + k];
                float4 x1 = *(const float4*)&x_lds[rg + 1][kc + k];
                float4 x2v = *(const float4*)&x_lds[rg + 2][kc + k];
                float4 x3 = *(const float4*)&x_lds[rg + 3][kc + k];
                const float* wp = wbuf + k * 128 + j;
#define G1K(comp, off) { float2 wv = *(const float2*)(wp + (off) * 128); \
    acc[0][0] += x0.comp * wv.x; acc[0][1] += x0.comp * wv.y; \
    acc[1][0] += x1.comp * wv.x; acc[1][1] += x1.comp * wv.y; \
    acc[2][0] += x2v.comp * wv.x; acc[2][1] += x2v.comp * wv.y; \
    acc[3][0] += x3.comp * wv.x; acc[3][1] += x3.comp * wv.y; }
                G1K(x, 0) G1K(y, 1) G1K(z, 2) G1K(w, 3)
#undef G1K
            }
        }
        if (!is_gate) {
            float2 wt = *(const float2*)&w1[288 * 128 + j];
#pragma unroll
            for (int ri = 0; ri < 4; ri++) {
                float xb = x_lds[rg + ri][288];
                acc[ri][0] += xb * wt.x; acc[ri][1] += xb * wt.y;
            }
        }
#pragma unroll
        for (int ri = 0; ri < 4; ri++)
            *(float2*)&h1_lds[rg + ri][j] = make_float2(lrelu(acc[ri][0]), lrelu(acc[ri][1]));
    }
    __syncthreads();

    // ---------- GEMM2: (TN x 128) @ (128 x 256) + b2 (+relu); async LDS-staged ----------
    {
        const int j = (tid & 63) * 4;
        const int rg = (tid >> 6) * 4;
        float acc[4][4];
        float4 bv = *(const float4*)&b2[j];
#pragma unroll
        for (int ri = 0; ri < 4; ri++) { acc[ri][0] = bv.x; acc[ri][1] = bv.y; acc[ri][2] = bv.z; acc[ri][3] = bv.w; }

        const float4* wg2 = (const float4*)w2;
        float4* w4 = (float4*)wbuf;
        ta = wg2[tid]; tb = wg2[tid + 256]; tc = wg2[tid + 512]; td = wg2[tid + 768];
        for (int c = 0; c < 8; ++c) {            // 8 chunks of 16 k (16x256 = 1024 float4)
            __syncthreads();
            w4[tid] = ta; w4[tid + 256] = tb; w4[tid + 512] = tc; w4[tid + 768] = td;
            if (c < 7) {
                const float4* gn = wg2 + (size_t)(c + 1) * 1024;
                ta = gn[tid]; tb = gn[tid + 256]; tc = gn[tid + 512]; td = gn[tid + 768];
            }
            __syncthreads();
            const int kc = c * 16;
#pragma unroll 2
            for (int k = 0; k < 16; k += 4) {
                float4 x0 = *(const float4*)&h1_lds[rg + 0][kc + k];
                float4 x1 = *(const float4*)&h1_lds[rg + 1][kc + k];
                float4 x2v = *(const float4*)&h1_lds[rg + 2][kc + k];
                float4 x3 = *(const float4*)&h1_lds[rg + 3][kc + k];
                const float* wp = wbuf + k * 256 + j;
#define G2K(comp, off) { float4 wv = *(const float4*)(wp + (off) * 256); \
    acc[0][0] += x0.comp * wv.x; acc[0][1] += x0.comp * wv.y; acc[0][2] += x0.comp * wv.z; acc[0][3] += x0.comp * wv.w; \
    acc[1][0] += x1.comp * wv.x; acc[1][1] += x1.comp * wv.y; acc[1][2] += x1.comp * wv.z; acc[1][3] += x1.comp * wv.w; \
    acc[2][0] += x2v.comp * wv.x; acc[2][1] += x2v.comp * wv.y; acc[2][2] += x2v.comp * wv.z; acc[2][3] += x2v.comp * wv.w; \
    acc[3][0] += x3.comp * wv.x; acc[3][1] += x3.comp * wv.y; acc[3][2] += x3.comp * wv.z; acc[3][3] += x3.comp * wv.w; }
                G2K(x, 0) G2K(y, 1) G2K(z, 2) G2K(w, 3)
#undef G2K
            }
        }
        float4 avj = *(const float4*)&av[64 + j];
#pragma unroll
        for (int ri = 0; ri < 4; ri++) {
            if (apply_relu) {
#pragma unroll
                for (int ci = 0; ci < 4; ci++) acc[ri][ci] = fmaxf(acc[ri][ci], 0.f);
            }
            *(float4*)&nexth[(node0 + rg + ri) * HD + j] =
                make_float4(acc[ri][0], acc[ri][1], acc[ri][2], acc[ri][3]);
            // hoisted sdot for next level's attention: dot(next_h_row, av[64:320])
            float p = acc[ri][0] * avj.x + acc[ri][1] * avj.y + acc[ri][2] * avj.z + acc[ri][3] * avj.w;
#pragma unroll
            for (int off = 1; off < 64; off <<= 1) p += __shfl_xor(p, off);
            if ((tid & 63) == 0) sdot_next[node0 + rg + ri] = p;
        }
    }
}

// ---------------- final kernel: glob mlp + concat + out mlp (fused) ----------------
__global__ __launch_bounds__(256) void final_kernel(
    const float* __restrict__ prevh, const float* __restrict__ pofeat,
    const float* __restrict__ gl_w1, const float* __restrict__ gl_b1,
    const float* __restrict__ gl_w2, const float* __restrict__ gl_b2,
    const float* __restrict__ o_w1, const float* __restrict__ o_b1,
    const float* __restrict__ o_w2, const float* __restrict__ o_b2,
    float* __restrict__ out)
{
    __shared__ float x2[TN][516];
    __shared__ float g1[TN][132];
    __shared__ float wbuf[4096];
    __shared__ float ow2_lds[256];

    const int tid = threadIdx.x;
    const int node0 = blockIdx.x * TN;
    const int j = (tid & 63) * 4;
    const int rg = (tid >> 6) * 4;

    const float4* wgl = (const float4*)gl_w2;
    float4 ta = wgl[tid], tb = wgl[tid + 256], tc = wgl[tid + 512], td = wgl[tid + 768];

    for (int q = tid; q < TN * 64; q += 256) {
        int i = q >> 6, c4 = (q & 63) * 4;
        *(float4*)&x2[i][c4] = *(const float4*)&prevh[(node0 + i) * HD + c4];
    }
    for (int t = tid; t < TN * 128; t += 256) {
        int i = t >> 7, jj = t & 127;
        g1[i][jj] = lrelu(pofeat[node0 + i] * gl_w1[jj] + gl_b1[jj]);
    }
    ow2_lds[tid] = o_w2[tid];

    // glob layer 2: (TN x 128)@(128 x 256) -> x2 cols 256..511, async staged
    {
        float acc[4][4];
        float4 bv = *(const float4*)&gl_b2[j];
#pragma unroll
        for (int ri = 0; ri < 4; ri++) { acc[ri][0] = bv.x; acc[ri][1] = bv.y; acc[ri][2] = bv.z; acc[ri][3] = bv.w; }
        float4* w4 = (float4*)wbuf;
        for (int c = 0; c < 8; ++c) {
            __syncthreads();
            w4[tid] = ta; w4[tid + 256] = tb; w4[tid + 512] = tc; w4[tid + 768] = td;
            if (c < 7) {
                const float4* gn = wgl + (size_t)(c + 1) * 1024;
                ta = gn[tid]; tb = gn[tid + 256]; tc = gn[tid + 512]; td = gn[tid + 768];
            } else {
                const float4* gn = (const float4*)o_w1;   // prefetch out1 chunk 0
                ta = gn[tid]; tb = gn[tid + 256]; tc = gn[tid + 512]; td = gn[tid + 768];
            }
            __syncthreads();
            const int kc = c * 16;
#pragma unroll 2
            for (int k = 0; k < 16; k += 4) {
                float4 x0 = *(const float4*)&g1[rg + 0][kc + k];
                float4 x1 = *(const float4*)&g1[rg + 1][kc + k];
                float4 x2v = *(const float4*)&g1[rg + 2][kc + k];
                float4 x3 = *(const float4*)&g1[rg + 3][kc + k];
                const float* wp = wbuf + k * 256 + j;
#define GLK(comp, off) { float4 wv = *(const float4*)(wp + (off) * 256); \
    acc[0][0] += x0.comp * wv.x; acc[0][1] += x0.comp * wv.y; acc[0][2] += x0.comp * wv.z; acc[0][3] += x0.comp * wv.w; \
    acc[1][0] += x1.comp * wv.x; acc[1][1] += x1.comp * wv.y; acc[1][2] += x1.comp * wv.z; acc[1][3] += x1.comp * wv.w; \
    acc[2][0] += x2v.comp * wv.x; acc[2][1] += x2v.comp * wv.y; acc[2][2] += x2v.comp * wv.z; acc[2][3] += x2v.comp * wv.w; \
    acc[3][0] += x3.comp * wv.x; acc[3][1] += x3.comp * wv.y; acc[3][2] += x3.comp * wv.z; acc[3][3] += x3.comp * wv.w; }
                GLK(x, 0) GLK(y, 1) GLK(z, 2) GLK(w, 3)
#undef GLK
            }
        }
        __syncthreads();
#pragma unroll
        for (int ri = 0; ri < 4; ri++)
            *(float4*)&x2[rg + ri][256 + j] = make_float4(acc[ri][0], acc[ri][1], acc[ri][2], acc[ri][3]);
        __syncthreads();
    }

    // out layer 1 (async staged, 32 chunks) fused with out layer 2 (wave reduction)
    {
        float acc[4][4];
        float4 bv = *(const float4*)&o_b1[j];
#pragma unroll
        for (int ri = 0; ri < 4; ri++) { acc[ri][0] = bv.x; acc[ri][1] = bv.y; acc[ri][2] = bv.z; acc[ri][3] = bv.w; }
        const float4* wo = (const float4*)o_w1;
        float4* w4 = (float4*)wbuf;
        for (int c = 0; c < 32; ++c) {
            __syncthreads();
            w4[tid] = ta; w4[tid + 256] = tb; w4[tid + 512] = tc; w4[tid + 768] = td;
            if (c < 31) {
                const float4* gn = wo + (size_t)(c + 1) * 1024;
                ta = gn[tid]; tb = gn[tid + 256]; tc = gn[tid + 512]; td = gn[tid + 768];
            }
            __syncthreads();
            const int kc = c * 16;
#pragma unroll 2
            for (int k = 0; k < 16; k += 4) {
                float4 x0 = *(const float4*)&x2[rg + 0][kc + k];
                float4 x1 = *(const float4*)&x2[rg + 1][kc + k];
                float4 x2v = *(const float4*)&x2[rg + 2][kc + k];
                float4 x3 = *(const float4*)&x2[rg + 3][kc + k];
                const float* wp = wbuf + k * 256 + j;
#define O1K(comp, off) { float4 wv = *(const float4*)(wp + (off) * 256); \
    acc[0][0] += x0.comp * wv.x; acc[0][1] += x0.comp * wv.y; acc[0][2] += x0.comp * wv.z; acc[0][3] += x0.comp * wv.w; \
    acc[1][0] += x1.comp * wv.x; acc[1][1] += x1.comp * wv.y; acc[1][2] += x1.comp * wv.z; acc[1][3] += x1.comp * wv.w; \
    acc[2][0] += x2v.comp * wv.x; acc[2][1] += x2v.comp * wv.y; acc[2][2] += x2v.comp * wv.z; acc[2][3] += x2v.comp * wv.w; \
    acc[3][0] += x3.comp * wv.x; acc[3][1] += x3.comp * wv.y; acc[3][2] += x3.comp * wv.z; acc[3][3] += x3.comp * wv.w; }
                O1K(x, 0) O1K(y, 1) O1K(z, 2) O1K(w, 3)
#undef O1K
            }
        }
        // out layer 2: each wave's 64 lanes cover cols 0..255 for rows rg..rg+3
        float4 wv = *(const float4*)&ow2_lds[j];
        float ob = o_b2[0];
#pragma unroll
        for (int ri = 0; ri < 4; ri++) {
            float p = lrelu(acc[ri][0]) * wv.x + lrelu(acc[ri][1]) * wv.y
                    + lrelu(acc[ri][2]) * wv.z + lrelu(acc[ri][3]) * wv.w;
#pragma unroll
            for (int off = 1; off < 64; off <<= 1) p += __shfl_xor(p, off);
            if ((tid & 63) == 0) out[node0 + rg + ri] = p + ob;
        }
    }
}

extern "C" void kernel_launch(void* const* d_in, const int* in_sizes, int n_in,
                              void* d_out, int out_size, void* d_ws, size_t ws_size,
                              hipStream_t stream)
{
    const float* delay    = (const float*)d_in[0];
    const float* feat     = (const float*)d_in[1];
    const float* bitpos   = (const float*)d_in[2];
    const float* pofeat   = (const float*)d_in[3];
    const int*   srcidx   = (const int*)  d_in[4];
    const float* pi_w1    = (const float*)d_in[5];
    const float* pi_b1    = (const float*)d_in[6];
    const float* pi_w2    = (const float*)d_in[7];
    const float* pi_b2    = (const float*)d_in[8];
    const float* gate_w1  = (const float*)d_in[9];
    const float* gate_b1  = (const float*)d_in[10];
    const float* gate_w2  = (const float*)d_in[11];
    const float* gate_b2  = (const float*)d_in[12];
    const float* mod_w1   = (const float*)d_in[13];
    const float* mod_b1   = (const float*)d_in[14];
    const float* mod_w2   = (const float*)d_in[15];
    const float* mod_b2   = (const float*)d_in[16];
    const float* type_w1  = (const float*)d_in[17];
    const float* type_b1  = (const float*)d_in[18];
    const float* type_w2  = (const float*)d_in[19];
    const float* type_b2  = (const float*)d_in[20];
    const float* pos_w1   = (const float*)d_in[21];
    const float* pos_b1   = (const float*)d_in[22];
    const float* pos_w2   = (const float*)d_in[23];
    const float* pos_b2   = (const float*)d_in[24];
    const float* attn_vec = (const float*)d_in[25];
    const float* glob_w1  = (const float*)d_in[26];
    const float* glob_b1  = (const float*)d_in[27];
    const float* glob_w2  = (const float*)d_in[28];
    const float* glob_b2  = (const float*)d_in[29];
    const float* out_w1   = (const float*)d_in[30];
    const float* out_b1   = (const float*)d_in[31];
    const float* out_w2   = (const float*)d_in[32];
    const float* out_b2   = (const float*)d_in[33];

    float* buf0 = (float*)d_ws;
    float* buf1 = buf0 + (size_t)NP * HD;
    float* sd0  = buf1 + (size_t)NP * HD;
    float* sd1  = sd0 + NP;

    pi_kernel<<<NP / TN, 256, 0, stream>>>(delay, pi_w1, pi_b1, pi_w2, pi_b2,
                                           attn_vec, buf0, sd0);

    for (int l = 0; l < NLVL; l++) {
        float* pv = (l & 1) ? buf1 : buf0;
        float* nx = (l & 1) ? buf0 : buf1;
        float* sp = (l & 1) ? sd1 : sd0;
        float* sn = (l & 1) ? sd0 : sd1;
        level_kernel<<<NP / TN, 256, 0, stream>>>(
            pv, nx, sp, sn, feat, bitpos, srcidx,
            gate_w1, gate_b1, gate_w2, gate_b2,
            mod_w1, mod_b1, mod_w2, mod_b2,
            type_w1, type_b1, type_w2, type_b2,
            pos_w1, pos_b1, pos_w2, pos_b2,
            attn_vec, l, (l != NLVL - 1) ? 1 : 0);
    }

    final_kernel<<<NP / TN, 256, 0, stream>>>(
        buf1, pofeat,
        glob_w1, glob_b1, glob_w2, glob_b2,
        out_w1, out_b1, out_w2, out_b2,
        (float*)d_out);
}

// Round 10
// 597.976 us; speedup vs baseline: 10.1528x; 1.0126x over previous
//
#include <hip/hip_runtime.h>
#include <math.h>

#define HD   256
#define FIN  32
#define NP   8192
#define PGH  4096
#define NLVL 15
#define TN   16    // nodes per block tile

__device__ __forceinline__ float lrelu(float x) { return x > 0.f ? x : 0.1f * x; }

// ---------------- pi kernel: prev_h = mlp(delay), + sdot epilogue ----------------
__global__ __launch_bounds__(256) void pi_kernel(
    const float* __restrict__ delay,
    const float* __restrict__ w1, const float* __restrict__ b1,
    const float* __restrict__ w2, const float* __restrict__ b2,
    const float* __restrict__ av,
    float* __restrict__ outh, float* __restrict__ sdot)
{
    __shared__ float g1[TN][132];
    const int tid = threadIdx.x;
    const int node0 = blockIdx.x * TN;

    for (int t = tid; t < TN * 128; t += 256) {
        int i = t >> 7, jj = t & 127;
        g1[i][jj] = lrelu(delay[node0 + i] * w1[jj] + b1[jj]);
    }
    __syncthreads();

    const int j = (tid & 63) * 4;
    const int rg = (tid >> 6) * 4;
    float acc[4][4];
    float4 bv = *(const float4*)&b2[j];
#pragma unroll
    for (int ri = 0; ri < 4; ri++) { acc[ri][0] = bv.x; acc[ri][1] = bv.y; acc[ri][2] = bv.z; acc[ri][3] = bv.w; }

#pragma unroll 2
    for (int k = 0; k < 128; k += 4) {
        float4 x0 = *(const float4*)&g1[rg + 0][k];
        float4 x1 = *(const float4*)&g1[rg + 1][k];
        float4 x2v = *(const float4*)&g1[rg + 2][k];
        float4 x3 = *(const float4*)&g1[rg + 3][k];
        const float* wp = w2 + (size_t)k * 256 + j;
#define PIK(comp, off) { float4 wv = *(const float4*)(wp + (off) * 256); \
    acc[0][0] += x0.comp * wv.x; acc[0][1] += x0.comp * wv.y; acc[0][2] += x0.comp * wv.z; acc[0][3] += x0.comp * wv.w; \
    acc[1][0] += x1.comp * wv.x; acc[1][1] += x1.comp * wv.y; acc[1][2] += x1.comp * wv.z; acc[1][3] += x1.comp * wv.w; \
    acc[2][0] += x2v.comp * wv.x; acc[2][1] += x2v.comp * wv.y; acc[2][2] += x2v.comp * wv.z; acc[2][3] += x2v.comp * wv.w; \
    acc[3][0] += x3.comp * wv.x; acc[3][1] += x3.comp * wv.y; acc[3][2] += x3.comp * wv.z; acc[3][3] += x3.comp * wv.w; }
        PIK(x, 0) PIK(y, 1) PIK(z, 2) PIK(w, 3)
#undef PIK
    }
    float4 avj = *(const float4*)&av[64 + j];
#pragma unroll
    for (int ri = 0; ri < 4; ri++) {
        *(float4*)&outh[(node0 + rg + ri) * HD + j] =
            make_float4(acc[ri][0], acc[ri][1], acc[ri][2], acc[ri][3]);
        float p = acc[ri][0] * avj.x + acc[ri][1] * avj.y + acc[ri][2] * avj.z + acc[ri][3] * avj.w;
#pragma unroll
        for (int off = 1; off < 64; off <<= 1) p += __shfl_xor(p, off);
        if ((tid & 63) == 0) sdot[node0 + rg + ri] = p;
    }
}

// ---------------- per-level kernel: 512 threads; blocks 0..255 gate, 256..511 mod ----------------
__global__ __launch_bounds__(512, 4) void level_kernel(
    const float* __restrict__ prevh, float* __restrict__ nexth,
    const float* __restrict__ sdot_prev, float* __restrict__ sdot_next,
    const float* __restrict__ feat, const float* __restrict__ bitpos,
    const int* __restrict__ srcidx,
    const float* __restrict__ g_w1, const float* __restrict__ g_b1,
    const float* __restrict__ g_w2, const float* __restrict__ g_b2,
    const float* __restrict__ m_w1, const float* __restrict__ m_b1,
    const float* __restrict__ m_w2, const float* __restrict__ m_b2,
    const float* __restrict__ t_w1, const float* __restrict__ t_b1,
    const float* __restrict__ t_w2, const float* __restrict__ t_b2,
    const float* __restrict__ p_w1, const float* __restrict__ p_b1,
    const float* __restrict__ p_w2, const float* __restrict__ p_b2,
    const float* __restrict__ av,
    int level, int apply_relu)
{
    __shared__ float x_lds[TN][292];
    __shared__ float h1_lds[TN][132];
    __shared__ float wbuf[2][4096];     // 32 KB double-buffered weight staging
    __shared__ int   src_lds[TN * 8];
    __shared__ float bp_lds[TN * 8];
    __shared__ float dstf_lds[TN][32];
    __shared__ float ztt_lds[TN][32];
    __shared__ float alpha_lds[TN * 8];
    __shared__ float xbp_lds[TN];
    __shared__ float av_lds[64];
    __shared__ float tw2av_lds[32];
    __shared__ float pw2av_lds[32];
    __shared__ float bias_av[2];

    const int tid = threadIdx.x;
    const bool is_gate = (blockIdx.x < 256);
    const int node0 = is_gate ? (blockIdx.x * TN) : (PGH + ((int)blockIdx.x - 256) * TN);

    const float* w1 = is_gate ? g_w1 : m_w1;
    const float* b1 = is_gate ? g_b1 : m_b1;
    const float* w2 = is_gate ? g_w2 : m_w2;
    const float* b2 = is_gate ? g_b2 : m_b2;
    const float4* wg1 = (const float4*)w1;

    // issue GEMM1 chunk-0 weight loads now; they land during the gather phase
    float4 ta = wg1[tid], tb = wg1[tid + 512];

    if (tid < TN * 8) src_lds[tid] = srcidx[(level * NP + node0) * 8 + tid];

    if (is_gate) {
        {
            int i = tid >> 5, k = tid & 31;                    // 512 = TN*32 exactly
            x_lds[i][256 + k] = feat[((level + 1) * NP + node0 + i) * FIN + k];
        }
        __syncthreads();
        // gather + per-channel softmax: thread = (half, channel), 4-node chunks
        {
            const int c = tid & 255, sh = (tid >> 8) * 8;
            for (int s0 = 0; s0 < 8; s0 += 4) {
                const int* spA = &src_lds[(sh + s0 + 0) * 8];
                const int* spB = &src_lds[(sh + s0 + 1) * 8];
                const int* spC = &src_lds[(sh + s0 + 2) * 8];
                const int* spD = &src_lds[(sh + s0 + 3) * 8];
                float ma[8], mb[8], mc[8], md[8];
#pragma unroll
                for (int f = 0; f < 8; f++) ma[f] = prevh[spA[f] * HD + c];
#pragma unroll
                for (int f = 0; f < 8; f++) mb[f] = prevh[spB[f] * HD + c];
#pragma unroll
                for (int f = 0; f < 8; f++) mc[f] = prevh[spC[f] * HD + c];
#pragma unroll
                for (int f = 0; f < 8; f++) md[f] = prevh[spD[f] * HD + c];
                float mxa = -1e30f, mxb = -1e30f, mxc = -1e30f, mxd = -1e30f;
#pragma unroll
                for (int f = 0; f < 8; f++) {
                    mxa = fmaxf(mxa, ma[f]); mxb = fmaxf(mxb, mb[f]);
                    mxc = fmaxf(mxc, mc[f]); mxd = fmaxf(mxd, md[f]);
                }
                float sa = 0.f, wsa = 0.f, sb = 0.f, wsb = 0.f;
                float sc = 0.f, wsc = 0.f, sd = 0.f, wsd = 0.f;
#pragma unroll
                for (int f = 0; f < 8; f++) {
                    float ea = __expf(ma[f] - mxa); sa += ea; wsa += ma[f] * ea;
                    float eb = __expf(mb[f] - mxb); sb += eb; wsb += mb[f] * eb;
                    float ec = __expf(mc[f] - mxc); sc += ec; wsc += mc[f] * ec;
                    float ed = __expf(md[f] - mxd); sd += ed; wsd += md[f] * ed;
                }
                x_lds[sh + s0 + 0][c] = wsa / sa;
                x_lds[sh + s0 + 1][c] = wsb / sb;
                x_lds[sh + s0 + 2][c] = wsc / sc;
                x_lds[sh + s0 + 3][c] = wsd / sd;
            }
        }
        __syncthreads();
    } else {
        if (tid < TN * 8) bp_lds[tid] = bitpos[(level * NP + node0) * 8 + tid];
        {
            int i = tid >> 5, k = tid & 31;
            dstf_lds[i][k] = feat[((level + 1) * NP + node0 + i) * FIN + k];
        }
        if (tid < 64) av_lds[tid] = av[tid];
        __syncthreads();

        // ztt = lrelu(dstf @ t_w1 + t_b1): one output per thread (512 = 16*32)
        {
            int i = tid >> 5, jj = tid & 31;
            float a = t_b1[jj];
#pragma unroll 8
            for (int k = 0; k < 32; k++) a += dstf_lds[i][k] * t_w1[k * 32 + jj];
            ztt_lds[i][jj] = lrelu(a);
        }
        // fold attn_vec through second MLP layers (exact linear reassociation)
        if (tid < 32) {
            float s = 0.f;
#pragma unroll 8
            for (int jj = 0; jj < 32; jj++) s += t_w2[tid * 32 + jj] * av_lds[jj];
            tw2av_lds[tid] = s;
        } else if (tid < 64) {
            int k = tid - 32;
            float s = 0.f;
#pragma unroll 8
            for (int jj = 0; jj < 32; jj++) s += p_w2[k * 32 + jj] * av_lds[32 + jj];
            pw2av_lds[k] = s;
        } else if (tid == 64) {
            float s = 0.f;
#pragma unroll 8
            for (int jj = 0; jj < 32; jj++) s += t_b2[jj] * av_lds[jj];
            bias_av[0] = s;
        } else if (tid == 65) {
            float s = 0.f;
#pragma unroll 8
            for (int jj = 0; jj < 32; jj++) s += p_b2[jj] * av_lds[32 + jj];
            bias_av[1] = s;
        }
        __syncthreads();

        // logits + softmax over fanin: first 256 threads, tid = i*16 + f*2 + jg
        if (tid < 256) {
            const int jg = tid & 1, f = (tid >> 1) & 7, i = tid >> 4;
            const float sv = sdot_prev[src_lds[i * 8 + f]];   // hoisted row dot
            const float bpv = bp_lds[i * 8 + f];
            float part = 0.f;
            const int k0 = jg * 16;
#pragma unroll
            for (int k = k0; k < k0 + 16; k++) {
                float h1pk = lrelu(bpv * p_w1[k] + p_b1[k]);
                part += h1pk * pw2av_lds[k];
                part += ztt_lds[i][k] * tw2av_lds[k];
            }
            part += __shfl_xor(part, 1);
            float logit = part + bias_av[0] + bias_av[1] + sv;
            float mx = logit;
            mx = fmaxf(mx, __shfl_xor(mx, 2));
            mx = fmaxf(mx, __shfl_xor(mx, 4));
            mx = fmaxf(mx, __shfl_xor(mx, 8));
            float e = __expf(logit - mx);
            float ssum = e;
            ssum += __shfl_xor(ssum, 2);
            ssum += __shfl_xor(ssum, 4);
            ssum += __shfl_xor(ssum, 8);
            float alpha = e / ssum;
            if (jg == 0) alpha_lds[i * 8 + f] = alpha;
            float ab = alpha * bpv;
            ab += __shfl_xor(ab, 2);
            ab += __shfl_xor(ab, 4);
            ab += __shfl_xor(ab, 8);
            if ((tid & 15) == 0) xbp_lds[i] = ab;
        }
        __syncthreads();

        // neigh_m: thread = (half, channel), 4-node chunks; assemble x
        {
            const int c = tid & 255, sh = (tid >> 8) * 8;
            for (int s0 = 0; s0 < 8; s0 += 4) {
                const int* spA = &src_lds[(sh + s0 + 0) * 8];
                const int* spB = &src_lds[(sh + s0 + 1) * 8];
                const int* spC = &src_lds[(sh + s0 + 2) * 8];
                const int* spD = &src_lds[(sh + s0 + 3) * 8];
                float ma[8], mb[8], mc[8], md[8];
#pragma unroll
                for (int f = 0; f < 8; f++) ma[f] = prevh[spA[f] * HD + c];
#pragma unroll
                for (int f = 0; f < 8; f++) mb[f] = prevh[spB[f] * HD + c];
#pragma unroll
                for (int f = 0; f < 8; f++) mc[f] = prevh[spC[f] * HD + c];
#pragma unroll
                for (int f = 0; f < 8; f++) md[f] = prevh[spD[f] * HD + c];
                const float* apA = &alpha_lds[(sh + s0 + 0) * 8];
                const float* apB = &alpha_lds[(sh + s0 + 1) * 8];
                const float* apC = &alpha_lds[(sh + s0 + 2) * 8];
                const float* apD = &alpha_lds[(sh + s0 + 3) * 8];
                float aa = 0.f, ab2 = 0.f, ac = 0.f, ad = 0.f;
#pragma unroll
                for (int f = 0; f < 8; f++) {
                    aa  += apA[f] * ma[f]; ab2 += apB[f] * mb[f];
                    ac  += apC[f] * mc[f]; ad  += apD[f] * md[f];
                }
                x_lds[sh + s0 + 0][c] = aa;
                x_lds[sh + s0 + 1][c] = ab2;
                x_lds[sh + s0 + 2][c] = ac;
                x_lds[sh + s0 + 3][c] = ad;
            }
        }
        if (tid < TN) x_lds[tid][256] = xbp_lds[tid];
        {
            int i = tid >> 5, k = tid & 31;
            x_lds[i][257 + k] = dstf_lds[i][k];
        }
        __syncthreads();
    }

    // ---------- GEMM1: (TN x K1) @ (K1 x 128) + b1, leaky; dbuf LDS-staged ----------
    {
        const int j = (tid & 63) * 2;
        const int rg = (tid >> 6) * 2;
        float acc[2][2];
        float2 bv = *(const float2*)&b1[j];
#pragma unroll
        for (int ri = 0; ri < 2; ri++) { acc[ri][0] = bv.x; acc[ri][1] = bv.y; }

        for (int c = 0; c < 9; ++c) {            // 9 chunks of 32 k (32x128 = 1024 f4)
            float* buf = wbuf[c & 1];
            float4* w4 = (float4*)buf;
            w4[tid] = ta; w4[tid + 512] = tb;
            if (c < 8) {
                const float4* gn = wg1 + (size_t)(c + 1) * 1024;
                ta = gn[tid]; tb = gn[tid + 512];
            }
            __syncthreads();
            const int kc = c * 32;
#pragma unroll 2
            for (int k = 0; k < 32; k += 4) {
                float4 x0 = *(const float4*)&x_lds[rg + 0][kc + k];
                float4 x1 = *(const float4*)&x_lds[rg + 1][kc + k];
                const float* wp = buf + k * 128 + j;
#define G1K(comp, off) { float2 wv = *(const float2*)(wp + (off) * 128); \
    acc[0][0] += x0.comp * wv.x; acc[0][1] += x0.comp * wv.y; \
    acc[1][0] += x1.comp * wv.x; acc[1][1] += x1.comp * wv.y; }
                G1K(x, 0) G1K(y, 1) G1K(z, 2) G1K(w, 3)
#undef G1K
            }
        }
        if (!is_gate) {
            float2 wt = *(const float2*)&w1[288 * 128 + j];
#pragma unroll
            for (int ri = 0; ri < 2; ri++) {
                float xb = x_lds[rg + ri][288];
                acc[ri][0] += xb * wt.x; acc[ri][1] += xb * wt.y;
            }
        }
        // issue GEMM2 chunk-0 loads; they land during the epilogue + barrier
        {
            const float4* wg2 = (const float4*)w2;
            ta = wg2[tid]; tb = wg2[tid + 512];
        }
#pragma unroll
        for (int ri = 0; ri < 2; ri++)
            *(float2*)&h1_lds[rg + ri][j] = make_float2(lrelu(acc[ri][0]), lrelu(acc[ri][1]));
    }
    __syncthreads();

    // ---------- GEMM2: (TN x 128) @ (128 x 256) + b2 (+relu) + sdot; dbuf staged ----------
    {
        const int j = (tid & 63) * 4;
        const int rg = (tid >> 6) * 2;
        float acc[2][4];
        float4 bv = *(const float4*)&b2[j];
#pragma unroll
        for (int ri = 0; ri < 2; ri++) { acc[ri][0] = bv.x; acc[ri][1] = bv.y; acc[ri][2] = bv.z; acc[ri][3] = bv.w; }

        const float4* wg2 = (const float4*)w2;
        for (int c = 0; c < 8; ++c) {            // 8 chunks of 16 k (16x256 = 1024 f4)
            float* buf = wbuf[c & 1];
            float4* w4 = (float4*)buf;
            w4[tid] = ta; w4[tid + 512] = tb;
            if (c < 7) {
                const float4* gn = wg2 + (size_t)(c + 1) * 1024;
                ta = gn[tid]; tb = gn[tid + 512];
            }
            __syncthreads();
            const int kc = c * 16;
#pragma unroll 2
            for (int k = 0; k < 16; k += 4) {
                float4 x0 = *(const float4*)&h1_lds[rg + 0][kc + k];
                float4 x1 = *(const float4*)&h1_lds[rg + 1][kc + k];
                const float* wp = buf + k * 256 + j;
#define G2K(comp, off) { float4 wv = *(const float4*)(wp + (off) * 256); \
    acc[0][0] += x0.comp * wv.x; acc[0][1] += x0.comp * wv.y; acc[0][2] += x0.comp * wv.z; acc[0][3] += x0.comp * wv.w; \
    acc[1][0] += x1.comp * wv.x; acc[1][1] += x1.comp * wv.y; acc[1][2] += x1.comp * wv.z; acc[1][3] += x1.comp * wv.w; }
                G2K(x, 0) G2K(y, 1) G2K(z, 2) G2K(w, 3)
#undef G2K
            }
        }
        float4 avj = *(const float4*)&av[64 + j];
#pragma unroll
        for (int ri = 0; ri < 2; ri++) {
            if (apply_relu) {
#pragma unroll
                for (int ci = 0; ci < 4; ci++) acc[ri][ci] = fmaxf(acc[ri][ci], 0.f);
            }
            *(float4*)&nexth[(node0 + rg + ri) * HD + j] =
                make_float4(acc[ri][0], acc[ri][1], acc[ri][2], acc[ri][3]);
            float p = acc[ri][0] * avj.x + acc[ri][1] * avj.y + acc[ri][2] * avj.z + acc[ri][3] * avj.w;
#pragma unroll
            for (int off = 1; off < 64; off <<= 1) p += __shfl_xor(p, off);
            if ((tid & 63) == 0) sdot_next[node0 + rg + ri] = p;
        }
    }
}

// ---------------- final kernel: 512 threads; glob mlp + concat + out mlp (fused) ----------------
__global__ __launch_bounds__(512, 4) void final_kernel(
    const float* __restrict__ prevh, const float* __restrict__ pofeat,
    const float* __restrict__ gl_w1, const float* __restrict__ gl_b1,
    const float* __restrict__ gl_w2, const float* __restrict__ gl_b2,
    const float* __restrict__ o_w1, const float* __restrict__ o_b1,
    const float* __restrict__ o_w2, const float* __restrict__ o_b2,
    float* __restrict__ out)
{
    __shared__ float x2[TN][516];
    __shared__ float g1[TN][132];
    __shared__ float wbuf[2][4096];
    __shared__ float ow2_lds[256];

    const int tid = threadIdx.x;
    const int node0 = blockIdx.x * TN;
    const int j = (tid & 63) * 4;
    const int rg = (tid >> 6) * 2;

    const float4* wgl = (const float4*)gl_w2;
    float4 ta = wgl[tid], tb = wgl[tid + 512];

    for (int q = tid; q < TN * 64; q += 512) {
        int i = q >> 6, c4 = (q & 63) * 4;
        *(float4*)&x2[i][c4] = *(const float4*)&prevh[(node0 + i) * HD + c4];
    }
    for (int t = tid; t < TN * 128; t += 512) {
        int i = t >> 7, jj = t & 127;
        g1[i][jj] = lrelu(pofeat[node0 + i] * gl_w1[jj] + gl_b1[jj]);
    }
    if (tid < 256) ow2_lds[tid] = o_w2[tid];
    __syncthreads();

    // glob layer 2: (TN x 128)@(128 x 256) -> x2 cols 256..511, dbuf staged
    {
        float acc[2][4];
        float4 bv = *(const float4*)&gl_b2[j];
#pragma unroll
        for (int ri = 0; ri < 2; ri++) { acc[ri][0] = bv.x; acc[ri][1] = bv.y; acc[ri][2] = bv.z; acc[ri][3] = bv.w; }
        for (int c = 0; c < 8; ++c) {
            float* buf = wbuf[c & 1];
            float4* w4 = (float4*)buf;
            w4[tid] = ta; w4[tid + 512] = tb;
            if (c < 7) {
                const float4* gn = wgl + (size_t)(c + 1) * 1024;
                ta = gn[tid]; tb = gn[tid + 512];
            } else {
                const float4* gn = (const float4*)o_w1;   // prefetch out1 chunk 0
                ta = gn[tid]; tb = gn[tid + 512];
            }
            __syncthreads();
            const int kc = c * 16;
#pragma unroll 2
            for (int k = 0; k < 16; k += 4) {
                float4 x0 = *(const float4*)&g1[rg + 0][kc + k];
                float4 x1 = *(const float4*)&g1[rg + 1][kc + k];
                const float* wp = buf + k * 256 + j;
#define GLK(comp, off) { float4 wv = *(const float4*)(wp + (off) * 256); \
    acc[0][0] += x0.comp * wv.x; acc[0][1] += x0.comp * wv.y; acc[0][2] += x0.comp * wv.z; acc[0][3] += x0.comp * wv.w; \
    acc[1][0] += x1.comp * wv.x; acc[1][1] += x1.comp * wv.y; acc[1][2] += x1.comp * wv.z; acc[1][3] += x1.comp * wv.w; }
                GLK(x, 0) GLK(y, 1) GLK(z, 2) GLK(w, 3)
#undef GLK
            }
        }
#pragma unroll
        for (int ri = 0; ri < 2; ri++)
            *(float4*)&x2[rg + ri][256 + j] = make_float4(acc[ri][0], acc[ri][1], acc[ri][2], acc[ri][3]);
    }
    __syncthreads();

    // out layer 1 (dbuf staged, 32 chunks) fused with out layer 2 (wave reduction)
    {
        float acc[2][4];
        float4 bv = *(const float4*)&o_b1[j];
#pragma unroll
        for (int ri = 0; ri < 2; ri++) { acc[ri][0] = bv.x; acc[ri][1] = bv.y; acc[ri][2] = bv.z; acc[ri][3] = bv.w; }
        const float4* wo = (const float4*)o_w1;
        for (int c = 0; c < 32; ++c) {
            float* buf = wbuf[c & 1];
            float4* w4 = (float4*)buf;
            w4[tid] = ta; w4[tid + 512] = tb;
            if (c < 31) {
                const float4* gn = wo + (size_t)(c + 1) * 1024;
                ta = gn[tid]; tb = gn[tid + 512];
            }
            __syncthreads();
            const int kc = c * 16;
#pragma unroll 2
            for (int k = 0; k < 16; k += 4) {
                float4 x0 = *(const float4*)&x2[rg + 0][kc + k];
                float4 x1 = *(const float4*)&x2[rg + 1][kc + k];
                const float* wp = buf + k * 256 + j;
#define O1K(comp, off) { float4 wv = *(const float4*)(wp + (off) * 256); \
    acc[0][0] += x0.comp * wv.x; acc[0][1] += x0.comp * wv.y; acc[0][2] += x0.comp * wv.z; acc[0][3] += x0.comp * wv.w; \
    acc[1][0] += x1.comp * wv.x; acc[1][1] += x1.comp * wv.y; acc[1][2] += x1.comp * wv.z; acc[1][3] += x1.comp * wv.w; }
                O1K(x, 0) O1K(y, 1) O1K(z, 2) O1K(w, 3)
#undef O1K
            }
        }
        // out layer 2: each wave's 64 lanes cover cols 0..255 for rows rg, rg+1
        float4 wv = *(const float4*)&ow2_lds[j];
        float ob = o_b2[0];
#pragma unroll
        for (int ri = 0; ri < 2; ri++) {
            float p = lrelu(acc[ri][0]) * wv.x + lrelu(acc[ri][1]) * wv.y
                    + lrelu(acc[ri][2]) * wv.z + lrelu(acc[ri][3]) * wv.w;
#pragma unroll
            for (int off = 1; off < 64; off <<= 1) p += __shfl_xor(p, off);
            if ((tid & 63) == 0) out[node0 + rg + ri] = p + ob;
        }
    }
}

extern "C" void kernel_launch(void* const* d_in, const int* in_sizes, int n_in,
                              void* d_out, int out_size, void* d_ws, size_t ws_size,
                              hipStream_t stream)
{
    const float* delay    = (const float*)d_in[0];
    const float* feat     = (const float*)d_in[1];
    const float* bitpos   = (const float*)d_in[2];
    const float* pofeat   = (const float*)d_in[3];
    const int*   srcidx   = (const int*)  d_in[4];
    const float* pi_w1    = (const float*)d_in[5];
    const float* pi_b1    = (const float*)d_in[6];
    const float* pi_w2    = (const float*)d_in[7];
    const float* pi_b2    = (const float*)d_in[8];
    const float* gate_w1  = (const float*)d_in[9];
    const float* gate_b1  = (const float*)d_in[10];
    const float* gate_w2  = (const float*)d_in[11];
    const float* gate_b2  = (const float*)d_in[12];
    const float* mod_w1   = (const float*)d_in[13];
    const float* mod_b1   = (const float*)d_in[14];
    const float* mod_w2   = (const float*)d_in[15];
    const float* mod_b2   = (const float*)d_in[16];
    const float* type_w1  = (const float*)d_in[17];
    const float* type_b1  = (const float*)d_in[18];
    const float* type_w2  = (const float*)d_in[19];
    const float* type_b2  = (const float*)d_in[20];
    const float* pos_w1   = (const float*)d_in[21];
    const float* pos_b1   = (const float*)d_in[22];
    const float* pos_w2   = (const float*)d_in[23];
    const float* pos_b2   = (const float*)d_in[24];
    const float* attn_vec = (const float*)d_in[25];
    const float* glob_w1  = (const float*)d_in[26];
    const float* glob_b1  = (const float*)d_in[27];
    const float* glob_w2  = (const float*)d_in[28];
    const float* glob_b2  = (const float*)d_in[29];
    const float* out_w1   = (const float*)d_in[30];
    const float* out_b1   = (const float*)d_in[31];
    const float* out_w2   = (const float*)d_in[32];
    const float* out_b2   = (const float*)d_in[33];

    float* buf0 = (float*)d_ws;
    float* buf1 = buf0 + (size_t)NP * HD;
    float* sd0  = buf1 + (size_t)NP * HD;
    float* sd1  = sd0 + NP;

    pi_kernel<<<NP / TN, 256, 0, stream>>>(delay, pi_w1, pi_b1, pi_w2, pi_b2,
                                           attn_vec, buf0, sd0);

    for (int l = 0; l < NLVL; l++) {
        float* pv = (l & 1) ? buf1 : buf0;
        float* nx = (l & 1) ? buf0 : buf1;
        float* sp = (l & 1) ? sd1 : sd0;
        float* sn = (l & 1) ? sd0 : sd1;
        level_kernel<<<NP / TN, 512, 0, stream>>>(
            pv, nx, sp, sn, feat, bitpos, srcidx,
            gate_w1, gate_b1, gate_w2, gate_b2,
            mod_w1, mod_b1, mod_w2, mod_b2,
            type_w1, type_b1, type_w2, type_b2,
            pos_w1, pos_b1, pos_w2, pos_b2,
            attn_vec, l, (l != NLVL - 1) ? 1 : 0);
    }

    final_kernel<<<NP / TN, 512, 0, stream>>>(
        buf1, pofeat,
        glob_w1, glob_b1, glob_w2, glob_b2,
        out_w1, out_b1, out_w2, out_b2,
        (float*)d_out);
}